// Round 12
// baseline (69.918 us; speedup 1.0000x reference)
//
#include <hip/hip_runtime.h>
#include <math.h>

#define N 4096
#define D 128
#define NT 32                 // 4096/128 tiles per dim
#define NBLK (NT*(NT+1)/2)    // 528 tiles, one block each
#define LSTR 40               // padded LDS row stride (bf16 elems), 16B-aligned rows
#define BIGV 1e30f

typedef __bf16 bf16x8 __attribute__((ext_vector_type(8)));
typedef float  f32x4  __attribute__((ext_vector_type(4)));

// ---- device-scope (LLC coherence point) accessors ----
__device__ __forceinline__ void stg(float* p, float v) {
  __hip_atomic_store(p, v, __ATOMIC_RELAXED, __HIP_MEMORY_SCOPE_AGENT);
}
__device__ __forceinline__ float ldg1(const float* p) {
  return __hip_atomic_load((float*)p, __ATOMIC_RELAXED, __HIP_MEMORY_SCOPE_AGENT);
}
__device__ __forceinline__ unsigned ldu(const unsigned* p) {
  return __hip_atomic_load((unsigned*)p, __ATOMIC_RELAXED, __HIP_MEMORY_SCOPE_AGENT);
}

// ---- monotone IEEE-754 <-> uint key (bijective). max-key via enc; min via ~enc ----
__device__ __forceinline__ unsigned enc(float f) {
  unsigned u = __float_as_uint(f);
  return (u & 0x80000000u) ? ~u : (u | 0x80000000u);
}
__device__ __forceinline__ float dec(unsigned k) {
  unsigned u = (k & 0x80000000u) ? (k & 0x7FFFFFFFu) : ~k;
  return __uint_as_float(u);
}

// ---- DPP 16-lane reductions (VALU pipe, no LDS): xor1, xor2, ror4, ror8 ----
template<int CTRL>
__device__ __forceinline__ float dppf(float v) {
  int r = __builtin_amdgcn_update_dpp(0, __float_as_int(v), CTRL, 0xF, 0xF, true);
  return __int_as_float(r);
}
__device__ __forceinline__ float rsum16(float v) {
  v += dppf<0xB1>(v);   // quad_perm [1,0,3,2]  (xor 1)
  v += dppf<0x4E>(v);   // quad_perm [2,3,0,1]  (xor 2)
  v += dppf<0x124>(v);  // row_ror:4
  v += dppf<0x128>(v);  // row_ror:8
  return v;
}
__device__ __forceinline__ float rmin16(float v) {
  v = fminf(v, dppf<0xB1>(v));
  v = fminf(v, dppf<0x4E>(v));
  v = fminf(v, dppf<0x124>(v));
  v = fminf(v, dppf<0x128>(v));
  return v;
}
__device__ __forceinline__ float rmax16(float v) {
  v = fmaxf(v, dppf<0xB1>(v));
  v = fmaxf(v, dppf<0x4E>(v));
  v = fmaxf(v, dppf<0x124>(v));
  v = fmaxf(v, dppf<0x128>(v));
  return v;
}

// ---- split 8 f32 -> hi(+lo) bf16, rne/rne (proven bit-exact path) ----
__device__ __forceinline__ void cvt8(float4 v0, float4 v1, int4& hp, int4& lp) {
  float vf[8] = {v0.x, v0.y, v0.z, v0.w, v1.x, v1.y, v1.z, v1.w};
  unsigned h[8], l[8];
#pragma unroll
  for (int i = 0; i < 8; ++i) {
    unsigned u = __float_as_uint(vf[i]);
    unsigned hr = (u + 0x7FFFu + ((u >> 16) & 1u)) >> 16;
    float hv = __uint_as_float(hr << 16);
    unsigned ul = __float_as_uint(vf[i] - hv);
    unsigned lr = (ul + 0x7FFFu + ((ul >> 16) & 1u)) >> 16;
    h[i] = hr; l[i] = lr;
  }
  hp = make_int4((int)(h[0] | (h[1] << 16)), (int)(h[2] | (h[3] << 16)),
                 (int)(h[4] | (h[5] << 16)), (int)(h[6] | (h[7] << 16)));
  lp = make_int4((int)(l[0] | (l[1] << 16)), (int)(l[2] | (l[3] << 16)),
                 (int)(l[4] | (l[5] << 16)), (int)(l[6] | (l[7] << 16)));
}
__device__ __forceinline__ void cvt8hi(float4 v0, float4 v1, int4& hp) {
  float vf[8] = {v0.x, v0.y, v0.z, v0.w, v1.x, v1.y, v1.z, v1.w};
  unsigned h[8];
#pragma unroll
  for (int i = 0; i < 8; ++i) {
    unsigned u = __float_as_uint(vf[i]);
    h[i] = (u + 0x7FFFu + ((u >> 16) & 1u)) >> 16;
  }
  hp = make_int4((int)(h[0] | (h[1] << 16)), (int)(h[2] | (h[3] << 16)),
                 (int)(h[4] | (h[5] << 16)), (int)(h[6] | (h[7] << 16)));
}

// Off-diag: sim = hiA*hiB + hiA*loB (2 products). Diag: exact 3-product.
__device__ __forceinline__ void tile_gemm(f32x4 (&acc)[4][4],
    const float* __restrict__ x, int i0, int j0, bool diagp,
    __bf16* Ah, __bf16* Bh, __bf16* Bl, int tid)
{
  const int l = tid & 63, wid = tid >> 6;
  const int wr = wid >> 1, wc = wid & 1;
  const int g = l >> 4, c = l & 15;

  for (int kt = 0; kt < 4; ++kt) {
    __syncthreads();
    {
      int r = tid >> 2, q = tid & 3;
#pragma unroll
      for (int h2 = 0; h2 < 2; ++h2) {
        int row = r + h2 * 64;
        const float* src = &x[(i0 + row) * D + kt * 32 + q * 8];
        float4 v0 = *(const float4*)src, v1 = *(const float4*)(src + 4);
        int4 hp, lp;
        if (diagp) {
          cvt8(v0, v1, hp, lp);
          *(int4*)&Ah[row * LSTR + q * 8] = hp;
          *(int4*)&Bl[row * LSTR + q * 8] = lp;
        } else {
          cvt8hi(v0, v1, hp);
          *(int4*)&Ah[row * LSTR + q * 8] = hp;
          const float* srcb = &x[(j0 + row) * D + kt * 32 + q * 8];
          float4 w0 = *(const float4*)srcb, w1 = *(const float4*)(srcb + 4);
          cvt8(w0, w1, hp, lp);
          *(int4*)&Bh[row * LSTR + q * 8] = hp;
          *(int4*)&Bl[row * LSTR + q * 8] = lp;
        }
      }
    }
    __syncthreads();

    bf16x8 fah[4], fal[4];
#pragma unroll
    for (int m = 0; m < 4; ++m) {
      int row = wr * 64 + m * 16 + c;
      fah[m] = *(const bf16x8*)&Ah[row * LSTR + g * 8];
      if (diagp) fal[m] = *(const bf16x8*)&Bl[row * LSTR + g * 8];
    }
    const __bf16* BhP = diagp ? Ah : Bh;
#pragma unroll
    for (int n = 0; n < 4; ++n) {
      int col = wc * 64 + n * 16 + c;
      bf16x8 fbh = *(const bf16x8*)&BhP[col * LSTR + g * 8];
      bf16x8 fbl = *(const bf16x8*)&Bl[col * LSTR + g * 8];
#pragma unroll
      for (int m = 0; m < 4; ++m) {
        acc[m][n] = __builtin_amdgcn_mfma_f32_16x16x32_bf16(fah[m], fbh, acc[m][n], 0, 0, 0);
        acc[m][n] = __builtin_amdgcn_mfma_f32_16x16x32_bf16(fah[m], fbl, acc[m][n], 0, 0, 0);
        if (diagp)
          acc[m][n] = __builtin_amdgcn_mfma_f32_16x16x32_bf16(fal[m], fbh, acc[m][n], 0, 0, 0);
      }
    }
  }
}

__device__ __forceinline__ void epi_minmax_I(const f32x4 (&acc)[4][4],
    const int* tgI, const int* tgJ, float* redA, float* redB,
    unsigned* __restrict__ minE, unsigned* __restrict__ maxE, int i0, int tid)
{
  const int l = tid & 63, wid = tid >> 6;
  const int wr = wid >> 1, wc = wid & 1;
  const int g = l >> 4, c = l & 15;
  int tgc[4];
#pragma unroll
  for (int n = 0; n < 4; ++n) tgc[n] = tgJ[wc * 64 + n * 16 + c];
  __syncthreads();
#pragma unroll
  for (int m = 0; m < 4; ++m)
#pragma unroll
    for (int jj = 0; jj < 4; ++jj) {
      int row_loc = wr * 64 + m * 16 + g * 4 + jj;
      int trow = tgI[row_loc];
      float mn = BIGV, mx = -BIGV;
#pragma unroll
      for (int n = 0; n < 4; ++n) {
        float s = acc[m][n][jj];
        if (trow == tgc[n]) { if (s < 1.0f) mn = fminf(mn, s); }
        else                  mx = fmaxf(mx, s);
      }
      mn = rmin16(mn);
      mx = rmax16(mx);
      if (c == 0) { redA[wc * 128 + row_loc] = mn; redB[wc * 128 + row_loc] = mx; }
    }
  __syncthreads();
  if (tid < 128) {
    float mn = fminf(redA[tid], redA[128 + tid]);
    float mx = fmaxf(redB[tid], redB[128 + tid]);
    if (mn <  BIGV) atomicMax(&minE[i0 + tid], ~enc(mn));
    if (mx > -BIGV) atomicMax(&maxE[i0 + tid], enc(mx));
  }
}

__device__ __forceinline__ void epi_minmax_J(const f32x4 (&acc)[4][4],
    const int* tgI, const int* tgJ, float* redA, float* redB,
    unsigned* __restrict__ minE, unsigned* __restrict__ maxE, int j0, int tid)
{
  const int l = tid & 63, wid = tid >> 6;
  const int wr = wid >> 1, wc = wid & 1;
  const int g = l >> 4, c = l & 15;
  int tgc[4];
#pragma unroll
  for (int n = 0; n < 4; ++n) tgc[n] = tgJ[wc * 64 + n * 16 + c];
  __syncthreads();
  float mnn[4], mxx[4];
#pragma unroll
  for (int n = 0; n < 4; ++n) { mnn[n] = BIGV; mxx[n] = -BIGV; }
#pragma unroll
  for (int m = 0; m < 4; ++m)
#pragma unroll
    for (int jj = 0; jj < 4; ++jj) {
      int row_loc = wr * 64 + m * 16 + g * 4 + jj;
      int tcol = tgI[row_loc];
#pragma unroll
      for (int n = 0; n < 4; ++n) {
        float s = acc[m][n][jj];
        if (tgc[n] == tcol) { if (s < 1.0f) mnn[n] = fminf(mnn[n], s); }
        else                  mxx[n] = fmaxf(mxx[n], s);
      }
    }
#pragma unroll
  for (int n = 0; n < 4; ++n) {
#pragma unroll
    for (int msk = 16; msk < 64; msk <<= 1) {
      mnn[n] = fminf(mnn[n], __shfl_xor(mnn[n], msk, 64));
      mxx[n] = fmaxf(mxx[n], __shfl_xor(mxx[n], msk, 64));
    }
  }
  if (g == 0) {
#pragma unroll
    for (int n = 0; n < 4; ++n) {
      redA[wr * 128 + wc * 64 + n * 16 + c] = mnn[n];
      redB[wr * 128 + wc * 64 + n * 16 + c] = mxx[n];
    }
  }
  __syncthreads();
  if (tid < 128) {
    float mn = fminf(redA[tid], redA[128 + tid]);
    float mx = fmaxf(redB[tid], redB[128 + tid]);
    if (mn <  BIGV) atomicMax(&minE[j0 + tid], ~enc(mn));
    if (mx > -BIGV) atomicMax(&maxE[j0 + tid], enc(mx));
  }
}

__device__ __forceinline__ void epi_mine_I(const f32x4 (&acc)[4][4],
    const int* tgI, const int* tgJ,
    const float* rd0, const float* rd1, const float* rd2, const float* rd3,
    float* redA, float* redB, float* redC,
    float* __restrict__ possum, float* __restrict__ negsum,
    float* __restrict__ apsum,  float* __restrict__ ansum,
    int i0, int mode, int tid)
{
  const int l = tid & 63, wid = tid >> 6;
  const int wr = wid >> 1, wc = wid & 1;
  const int g = l >> 4, c = l & 15;
  int tgc[4];
#pragma unroll
  for (int n = 0; n < 4; ++n) tgc[n] = tgJ[wc * 64 + n * 16 + c];
  __syncthreads();
#pragma unroll
  for (int m = 0; m < 4; ++m)
#pragma unroll
    for (int jj = 0; jj < 4; ++jj) {
      int row_loc = wr * 64 + m * 16 + g * 4 + jj;
      int trow = tgI[row_loc];
      float mnp = rd0[row_loc], mxn = rd1[row_loc];
      float mg  = rd2[row_loc], wt  = rd3[row_loc];
      float ps = 0.f, ns = 0.f, cnt = 0.f;   // cnt = ap + 1024*an (exact)
#pragma unroll
      for (int n = 0; n < 4; ++n) {
        float s = acc[m][n][jj];
        bool same = (trow == tgc[n]);
        if (mode == 1) {
          float wsim = s * wt;
          if (same) {
            if (s < 1.0f && (mxn - s + mg > 0.f)) { ps += __expf(-2.f * (wsim - 0.5f)); cnt += 1.f; }
          } else {
            if (s + mg - mnp > 0.f) { ns += __expf(10.f * (wsim - 0.5f)); cnt += 1024.f; }
          }
        } else {
          if (same) {
            if (s < 1.0f) { ps += __expf(-2.f * (s - 0.5f - mg)); cnt += 1.f; }
          } else {
            ns += __expf(10.f * (s - 0.5f + mg)); cnt += 1024.f;
          }
        }
      }
      ps  = rsum16(ps);
      ns  = rsum16(ns);
      cnt = rsum16(cnt);
      if (c == 0) {
        redA[wc * 128 + row_loc] = ps;
        redB[wc * 128 + row_loc] = ns;
        redC[wc * 128 + row_loc] = cnt;
      }
    }
  __syncthreads();
  if (tid < 128) {
    float v;
    v = redA[tid] + redA[128 + tid]; if (v != 0.f) atomicAdd(&possum[i0 + tid], v);
    v = redB[tid] + redB[128 + tid]; if (v != 0.f) atomicAdd(&negsum[i0 + tid], v);
    float cnt = redC[tid] + redC[128 + tid];
    float an = floorf(cnt * (1.0f / 1024.0f));
    float ap = cnt - an * 1024.0f;
    if (ap != 0.f) atomicAdd(&apsum[i0 + tid], ap);
    if (an != 0.f) atomicAdd(&ansum[i0 + tid], an);
  }
}

__device__ __forceinline__ void epi_mine_J(const f32x4 (&acc)[4][4],
    const int* tgI, const int* tgJ,
    const float* rd0, const float* rd1, const float* rd2, const float* rd3,
    float* redA, float* redB, float* redC,
    float* __restrict__ possum, float* __restrict__ negsum,
    float* __restrict__ apsum,  float* __restrict__ ansum,
    int j0, int mode, int tid)
{
  const int l = tid & 63, wid = tid >> 6;
  const int wr = wid >> 1, wc = wid & 1;
  const int g = l >> 4, c = l & 15;
  int tgc[4];
#pragma unroll
  for (int n = 0; n < 4; ++n) tgc[n] = tgJ[wc * 64 + n * 16 + c];
  __syncthreads();
  float mnpJ[4], mxnJ[4], mgJ[4], wtJ[4];
#pragma unroll
  for (int n = 0; n < 4; ++n) {
    int jr = wc * 64 + n * 16 + c;
    mnpJ[n] = rd0[jr]; mxnJ[n] = rd1[jr]; mgJ[n] = rd2[jr]; wtJ[n] = rd3[jr];
  }
  float psn[4], nsn[4], cntn[4];
#pragma unroll
  for (int n = 0; n < 4; ++n) { psn[n] = 0.f; nsn[n] = 0.f; cntn[n] = 0.f; }
#pragma unroll
  for (int m = 0; m < 4; ++m)
#pragma unroll
    for (int jj = 0; jj < 4; ++jj) {
      int row_loc = wr * 64 + m * 16 + g * 4 + jj;
      int tcol = tgI[row_loc];
#pragma unroll
      for (int n = 0; n < 4; ++n) {
        float s = acc[m][n][jj];
        bool same = (tgc[n] == tcol);
        if (mode == 1) {
          float wsim = s * wtJ[n];
          if (same) {
            if (s < 1.0f && (mxnJ[n] - s + mgJ[n] > 0.f)) { psn[n] += __expf(-2.f * (wsim - 0.5f)); cntn[n] += 1.f; }
          } else {
            if (s + mgJ[n] - mnpJ[n] > 0.f) { nsn[n] += __expf(10.f * (wsim - 0.5f)); cntn[n] += 1024.f; }
          }
        } else {
          if (same) {
            if (s < 1.0f) { psn[n] += __expf(-2.f * (s - 0.5f - mgJ[n])); cntn[n] += 1.f; }
          } else {
            nsn[n] += __expf(10.f * (s - 0.5f + mgJ[n])); cntn[n] += 1024.f;
          }
        }
      }
    }
#pragma unroll
  for (int n = 0; n < 4; ++n) {
#pragma unroll
    for (int msk = 16; msk < 64; msk <<= 1) {
      psn[n]  += __shfl_xor(psn[n],  msk, 64);
      nsn[n]  += __shfl_xor(nsn[n],  msk, 64);
      cntn[n] += __shfl_xor(cntn[n], msk, 64);
    }
  }
  if (g == 0) {
#pragma unroll
    for (int n = 0; n < 4; ++n) {
      int col_loc = wc * 64 + n * 16 + c;
      redA[wr * 128 + col_loc] = psn[n];
      redB[wr * 128 + col_loc] = nsn[n];
      redC[wr * 128 + col_loc] = cntn[n];
    }
  }
  __syncthreads();
  if (tid < 128) {
    float v;
    v = redA[tid] + redA[128 + tid]; if (v != 0.f) atomicAdd(&possum[j0 + tid], v);
    v = redB[tid] + redB[128 + tid]; if (v != 0.f) atomicAdd(&negsum[j0 + tid], v);
    float cnt = redC[tid] + redC[128 + tid];
    float an = floorf(cnt * (1.0f / 1024.0f));
    float ap = cnt - an * 1024.0f;
    if (ap != 0.f) atomicAdd(&apsum[j0 + tid], ap);
    if (an != 0.f) atomicAdd(&ansum[j0 + tid], an);
  }
}

__global__ __launch_bounds__(256, 2)
void k_fused(const float* __restrict__ x, const int* __restrict__ tgt,
             const float* __restrict__ marg, const float* __restrict__ wgt,
             const int* __restrict__ hm, float* __restrict__ out,
             unsigned* __restrict__ minE, unsigned* __restrict__ maxE,
             float* __restrict__ possum, float* __restrict__ negsum,
             float* __restrict__ apsum,  float* __restrict__ ansum,
             float* __restrict__ lpart, unsigned* pcnt, unsigned* fcnt,
             unsigned* done)
{
  __shared__ __bf16 Ah[128*LSTR], Bh[128*LSTR], Bl[128*LSTR];   // 30720 B
  __shared__ int tgI[128], tgJ[128];
  __shared__ float rdI0[128], rdI1[128], rdI2[128], rdI3[128];
  __shared__ float rdJ0[128], rdJ1[128], rdJ2[128], rdJ3[128];
  __shared__ float redA[256], redB[256], redC[256];

  const int tid = threadIdx.x;
  const int bid = blockIdx.x;

  // ---- tile decode: one tile per block, triangular ----
  int I = 0, rem = bid;
  while (rem >= NT - I) { rem -= NT - I; ++I; }
  int J = I + rem;
  const int i0 = I * 128, j0 = J * 128;
  const bool diag = (I == J);

  if (tid < 128) { tgI[tid] = tgt[i0 + tid]; tgJ[tid] = tgt[j0 + tid]; }

  f32x4 acc[4][4];
#pragma unroll
  for (int m = 0; m < 4; ++m)
#pragma unroll
    for (int n = 0; n < 4; ++n) acc[m][n] = f32x4{0.f, 0.f, 0.f, 0.f};

  // ---- Phase 1: GEMM + min/max atomics ----
  tile_gemm(acc, x, i0, j0, diag, Ah, Bh, Bl, tid);
  epi_minmax_I(acc, tgI, tgJ, redA, redB, minE, maxE, i0, tid);
  if (!diag)
    epi_minmax_J(acc, tgI, tgJ, redA, redB, minE, maxE, j0, tid);

  // ---- per-panel dataflow sync: bump contribution counters, wait for my panels ----
  __syncthreads();                       // drains all waves' atomics (vmcnt(0) before barrier)
  if (tid == 0) {
    atomicAdd(&pcnt[I], 1u);
    if (!diag) atomicAdd(&pcnt[J], 1u);
    while (ldu(&pcnt[I]) < (unsigned)NT) __builtin_amdgcn_s_sleep(2);
    while (ldu(&pcnt[J]) < (unsigned)NT) __builtin_amdgcn_s_sleep(2);
  }
  asm volatile("" ::: "memory");
  __syncthreads();

  // ---- Phase 2: read final min/max + mining epilogue (atomicAdd) ----
  const int mode = hm[0];
  {
    const int half = tid >> 7, r = tid & 127;
    const int rowg = (half ? j0 : i0) + r;
    unsigned kmin = ldu(&minE[rowg]);
    unsigned kmax = ldu(&maxE[rowg]);
    float mn = (kmin == 0u) ?  BIGV : dec(~kmin);
    float mx = (kmax == 0u) ? -BIGV : dec(kmax);
    if (half == 0) { rdI0[r] = mn; rdI1[r] = mx; rdI2[r] = marg[rowg]; rdI3[r] = wgt[rowg]; }
    else           { rdJ0[r] = mn; rdJ1[r] = mx; rdJ2[r] = marg[rowg]; rdJ3[r] = wgt[rowg]; }
  }
  __syncthreads();
  epi_mine_I(acc, tgI, tgJ, rdI0, rdI1, rdI2, rdI3, redA, redB, redC,
             possum, negsum, apsum, ansum, i0, mode, tid);
  if (!diag)
    epi_mine_J(acc, tgI, tgJ, rdJ0, rdJ1, rdJ2, rdJ3, redA, redB, redC,
               possum, negsum, apsum, ansum, j0, mode, tid);

  // ---- bump mine-done counters; workers exit ----
  __syncthreads();
  if (tid == 0) {
    atomicAdd(&fcnt[I], 1u);
    if (!diag) atomicAdd(&fcnt[J], 1u);
  }
  if (bid >= 16) return;

  // ---- finals: block b owns rows [b*256, b*256+256) = panels 2b, 2b+1 ----
  if (tid == 0) {
    while (ldu(&fcnt[2 * bid])     < (unsigned)NT) __builtin_amdgcn_s_sleep(2);
    while (ldu(&fcnt[2 * bid + 1]) < (unsigned)NT) __builtin_amdgcn_s_sleep(2);
  }
  asm volatile("" ::: "memory");
  __syncthreads();

  {
    int i = bid * 256 + tid;
    float ps = ldg1(&possum[i]), ns = ldg1(&negsum[i]);
    float ap = ldg1(&apsum[i]),  an = ldg1(&ansum[i]);
    float loss_i = 1.0f * log1pf(ps) + 0.2f * log1pf(ns);
    if (mode == 1 && (ap + an) < 1.0f) { loss_i = 0.f; ap = 0.f; an = 0.f; }
    out[1 + i]     = ap;
    out[1 + N + i] = an;

    float v = loss_i;
#pragma unroll
    for (int msk = 32; msk; msk >>= 1) v += __shfl_down(v, msk, 64);
    if ((tid & 63) == 0) redA[tid >> 6] = v;
    __syncthreads();
    if (tid == 0) {
      stg(&lpart[bid], redA[0] + redA[1] + redA[2] + redA[3]);
      asm volatile("s_waitcnt vmcnt(0)" ::: "memory");
      unsigned o = __hip_atomic_fetch_add(done, 1u, __ATOMIC_ACQ_REL, __HIP_MEMORY_SCOPE_AGENT);
      if (o == 15u) {
        float s = 0.f;
#pragma unroll
        for (int k2 = 0; k2 < 16; ++k2) s += ldg1(&lpart[k2]);
        out[0] = s / (float)N;
      }
    }
  }
}

extern "C" void kernel_launch(void* const* d_in, const int* in_sizes, int n_in,
                              void* d_out, int out_size, void* d_ws, size_t ws_size,
                              hipStream_t stream)
{
  (void)in_sizes; (void)n_in; (void)out_size; (void)ws_size;
  const float* x    = (const float*)d_in[0];
  const int*   tgt  = (const int*)d_in[1];
  const float* marg = (const float*)d_in[2];
  const float* wgt  = (const float*)d_in[3];
  const int*   hm   = (const int*)d_in[4];
  float* out = (float*)d_out;

  // workspace: all zero-init (min uses ~enc keys so 0 == "no value")
  unsigned* minE   = (unsigned*)d_ws;          // N
  unsigned* maxE   = minE + N;                 // N
  float*    possum = (float*)(maxE + N);       // N
  float*    negsum = possum + N;               // N
  float*    apsum  = negsum + N;               // N
  float*    ansum  = apsum + N;                // N
  float*    lpart  = ansum + N;                // 16
  unsigned* pcnt   = (unsigned*)(lpart + 16);  // 32 phase-1 panel counters
  unsigned* fcnt   = pcnt + 32;                // 32 phase-2 panel counters
  unsigned* done   = fcnt + 32;                // 1

  hipMemsetAsync(d_ws, 0, (size_t)(6 * N + 16 + 65) * sizeof(unsigned), stream);
  k_fused<<<NBLK, 256, 0, stream>>>(x, tgt, marg, wgt, hm, out,
                                    minE, maxE, possum, negsum, apsum, ansum,
                                    lpart, pcnt, fcnt, done);
}

// Round 13
// 57.522 us; speedup vs baseline: 1.2155x; 1.2155x over previous
//
#include <hip/hip_runtime.h>
#include <math.h>

#define N 4096
#define D 128
#define NROW 16               // rows per block
#define NBLKS 256             // main-kernel grid
#define CH 256                // sim-cols (x-rows) per staged chunk
#define NCH 16                // chunks
#define BIGV 1e30f

typedef __bf16 bf16x8 __attribute__((ext_vector_type(8)));
typedef float  f32x4  __attribute__((ext_vector_type(4)));
typedef __attribute__((address_space(3))) unsigned lds_u32;
typedef const __attribute__((address_space(1))) unsigned glb_u32;

__device__ __forceinline__ void stg(float* p, float v) {
  __hip_atomic_store(p, v, __ATOMIC_RELAXED, __HIP_MEMORY_SCOPE_AGENT);
}
__device__ __forceinline__ float ldg1(const float* p) {
  return __hip_atomic_load((float*)p, __ATOMIC_RELAXED, __HIP_MEMORY_SCOPE_AGENT);
}

// split 8 f32 -> 8 bf16 hi + 8 bf16 lo (rne/rne; proven bit-exact path)
__device__ __forceinline__ void cvt8(float4 v0, float4 v1, int4& hp, int4& lp) {
  float vf[8] = {v0.x, v0.y, v0.z, v0.w, v1.x, v1.y, v1.z, v1.w};
  unsigned h[8], l[8];
#pragma unroll
  for (int i = 0; i < 8; ++i) {
    unsigned u = __float_as_uint(vf[i]);
    unsigned hr = (u + 0x7FFFu + ((u >> 16) & 1u)) >> 16;
    float hv = __uint_as_float(hr << 16);
    unsigned ul = __float_as_uint(vf[i] - hv);
    l[i] = (ul + 0x7FFFu + ((ul >> 16) & 1u)) >> 16;
    h[i] = hr;
  }
  hp = make_int4((int)(h[0] | (h[1] << 16)), (int)(h[2] | (h[3] << 16)),
                 (int)(h[4] | (h[5] << 16)), (int)(h[6] | (h[7] << 16)));
  lp = make_int4((int)(l[0] | (l[1] << 16)), (int)(l[2] | (l[3] << 16)),
                 (int)(l[4] | (l[5] << 16)), (int)(l[6] | (l[7] << 16)));
}
__device__ __forceinline__ void cvt8hi(float4 v0, float4 v1, int4& hp) {
  float vf[8] = {v0.x, v0.y, v0.z, v0.w, v1.x, v1.y, v1.z, v1.w};
  unsigned h[8];
#pragma unroll
  for (int i = 0; i < 8; ++i) {
    unsigned u = __float_as_uint(vf[i]);
    h[i] = (u + 0x7FFFu + ((u >> 16) & 1u)) >> 16;
  }
  hp = make_int4((int)(h[0] | (h[1] << 16)), (int)(h[2] | (h[3] << 16)),
                 (int)(h[4] | (h[5] << 16)), (int)(h[6] | (h[7] << 16)));
}

// ---- convert kernel: x -> bf16-hi, PRE-SWIZZLED 16B blocks within each 256B row ----
// stored position p16 = k16 ^ (row & 7)  (bijective involution; rule-21 pattern)
__global__ __launch_bounds__(256)
void k_conv(const float* __restrict__ x, ushort* __restrict__ xh)
{
  int gid = blockIdx.x * 256 + threadIdx.x;     // 65536 threads = 4096 rows x 16 blocks
  int row = gid >> 4, k16 = gid & 15;
  const float* ap = x + row * D + k16 * 8;
  float4 v0 = *(const float4*)ap, v1 = *(const float4*)(ap + 4);
  int4 hp;
  cvt8hi(v0, v1, hp);
  *(int4*)((char*)xh + row * 256 + ((k16 ^ (row & 7)) << 4)) = hp;
}

#define VMCNT(n) asm volatile("s_waitcnt vmcnt(" #n ")" ::: "memory")

// wave-private staging: wave w copies rows [w*32, w*32+32) of chunk ch_ (8 KB) linearly
#define STAGE(b_, ch_) do {                                                           \
    const char* gsrc_ = (const char*)xh + (size_t)(ch_) * 65536 + w * 8192 + l * 16;  \
    char* ldst_ = (char*)&Bbuf[b_][0] + w * 8192;                                     \
    _Pragma("unroll")                                                                 \
    for (int it_ = 0; it_ < 8; ++it_)                                                 \
      __builtin_amdgcn_global_load_lds((glb_u32*)(gsrc_ + it_ * 1024),                \
                                       (lds_u32*)(ldst_ + it_ * 1024), 16, 0, 0);     \
  } while (0)

__global__ __launch_bounds__(512, 2)
void k_main(const float* __restrict__ x, const int* __restrict__ tgt,
            const float* __restrict__ marg, const float* __restrict__ wgt,
            const int* __restrict__ hm, float* __restrict__ out,
            const ushort* __restrict__ xh, float* __restrict__ lpart,
            unsigned* __restrict__ done)
{
  __shared__ __bf16 Bbuf[2][32768];             // 2 x 64 KB chunk buffers
  __shared__ float redA[8][16], redB[8][16], redC[8][16], redD[8][16];
  __shared__ float finMn[16], finMx[16], finMg[16], finWt[16], lsRow[16];
  __shared__ int   tgRow[16];
  __shared__ float lsum[8];
  __shared__ unsigned lastf;

  const int tid = threadIdx.x;
  const int bid = blockIdx.x;
  const int w = tid >> 6, l = tid & 63;
  const int c = l & 15, g = l >> 4;
  const int i0 = bid * NROW;

  if (tid < 16) {
    tgRow[tid] = tgt[i0 + tid];
    finMg[tid] = marg[i0 + tid];
    finWt[tid] = wgt[i0 + tid];
  }

  // ---- A fragments (16 rows, hi+lo) in registers: row i0+c, k = kt*32 + g*8 ----
  bf16x8 Ah[4], Al[4];
#pragma unroll
  for (int kt = 0; kt < 4; ++kt) {
    const float* ap = x + (i0 + c) * D + kt * 32 + g * 8;
    float4 v0 = *(const float4*)ap, v1 = *(const float4*)(ap + 4);
    int4 hp, lp;
    cvt8(v0, v1, hp, lp);
    Ah[kt] = *(bf16x8*)&hp;
    Al[kt] = *(bf16x8*)&lp;
  }

  f32x4 acc[NCH][2];
#pragma unroll
  for (int ch = 0; ch < NCH; ++ch) {
    acc[ch][0] = f32x4{0.f, 0.f, 0.f, 0.f};
    acc[ch][1] = f32x4{0.f, 0.f, 0.f, 0.f};
  }

  // ---- K-loop: double-buffered wave-private staging, counted vmcnt, NO barriers ----
  STAGE(0, 0);
#pragma unroll
  for (int ch = 0; ch < NCH; ++ch) {
    if (ch + 1 < NCH) {
      STAGE((ch + 1) & 1, ch + 1);
      VMCNT(8);                 // wait chunk ch (next chunk's 8 loads stay in flight)
    } else {
      VMCNT(0);
    }
    __builtin_amdgcn_sched_barrier(0);
#pragma unroll
    for (int t = 0; t < 2; ++t) {
      const int colbase = ch * CH + w * 32 + t * 16;
      if (colbase == i0) {
        // diagonal tile: B-frags are the A-frag registers -> exact 3-product
#pragma unroll
        for (int kt = 0; kt < 4; ++kt) {
          acc[ch][t] = __builtin_amdgcn_mfma_f32_16x16x32_bf16(Ah[kt], Ah[kt], acc[ch][t], 0, 0, 0);
          acc[ch][t] = __builtin_amdgcn_mfma_f32_16x16x32_bf16(Ah[kt], Al[kt], acc[ch][t], 0, 0, 0);
          acc[ch][t] = __builtin_amdgcn_mfma_f32_16x16x32_bf16(Al[kt], Ah[kt], acc[ch][t], 0, 0, 0);
        }
      } else {
        const int lr = w * 32 + t * 16 + c;    // wave-private LDS row
#pragma unroll
        for (int kt = 0; kt < 4; ++kt) {
          const int k16 = kt * 4 + g;
          const char* bp = (const char*)&Bbuf[ch & 1][0] + lr * 256 + ((k16 ^ (lr & 7)) << 4);
          bf16x8 Bh = *(const bf16x8*)bp;
          acc[ch][t] = __builtin_amdgcn_mfma_f32_16x16x32_bf16(Ah[kt], Bh, acc[ch][t], 0, 0, 0);
          acc[ch][t] = __builtin_amdgcn_mfma_f32_16x16x32_bf16(Al[kt], Bh, acc[ch][t], 0, 0, 0);
        }
      }
    }
  }
  __syncthreads();   // tgRow/finMg/finWt ready; all compute done

  // ---- block-local min-pos / max-neg ----
  int trow[4];
  float mn4[4], mx4[4];
#pragma unroll
  for (int jj = 0; jj < 4; ++jj) {
    trow[jj] = tgRow[g * 4 + jj];
    mn4[jj] = BIGV; mx4[jj] = -BIGV;
  }
#pragma unroll
  for (int ch = 0; ch < NCH; ++ch)
#pragma unroll
    for (int t = 0; t < 2; ++t) {
      int cg = ch * CH + w * 32 + t * 16 + c;
      int tc = tgt[cg];
#pragma unroll
      for (int jj = 0; jj < 4; ++jj) {
        float s = acc[ch][t][jj];
        if (tc == trow[jj]) { if (s < 1.0f) mn4[jj] = fminf(mn4[jj], s); }
        else                  mx4[jj] = fmaxf(mx4[jj], s);
      }
    }
#pragma unroll
  for (int msk = 1; msk < 16; msk <<= 1)
#pragma unroll
    for (int jj = 0; jj < 4; ++jj) {
      mn4[jj] = fminf(mn4[jj], __shfl_xor(mn4[jj], msk, 64));
      mx4[jj] = fmaxf(mx4[jj], __shfl_xor(mx4[jj], msk, 64));
    }
  if (c == 0) {
#pragma unroll
    for (int jj = 0; jj < 4; ++jj) {
      redA[w][g * 4 + jj] = mn4[jj];
      redB[w][g * 4 + jj] = mx4[jj];
    }
  }
  __syncthreads();
  if (tid < 16) {
    float mn = BIGV, mx = -BIGV;
#pragma unroll
    for (int w8 = 0; w8 < 8; ++w8) {
      mn = fminf(mn, redA[w8][tid]);
      mx = fmaxf(mx, redB[w8][tid]);
    }
    finMn[tid] = mn; finMx[tid] = mx;
  }
  __syncthreads();

  // ---- mining epilogue over the same in-register acc ----
  const int mode = hm[0];
  float mnp[4], mxn[4], mg4[4], wt4[4];
  float ps4[4], ns4[4], ap4[4], an4[4];
#pragma unroll
  for (int jj = 0; jj < 4; ++jj) {
    int r = g * 4 + jj;
    mnp[jj] = finMn[r]; mxn[jj] = finMx[r]; mg4[jj] = finMg[r]; wt4[jj] = finWt[r];
    ps4[jj] = 0.f; ns4[jj] = 0.f; ap4[jj] = 0.f; an4[jj] = 0.f;
  }
#pragma unroll
  for (int ch = 0; ch < NCH; ++ch)
#pragma unroll
    for (int t = 0; t < 2; ++t) {
      int cg = ch * CH + w * 32 + t * 16 + c;
      int tc = tgt[cg];
#pragma unroll
      for (int jj = 0; jj < 4; ++jj) {
        float s = acc[ch][t][jj];
        bool same = (tc == trow[jj]);
        if (mode == 1) {
          float wsim = s * wt4[jj];
          if (same) {
            if (s < 1.0f && (mxn[jj] - s + mg4[jj] > 0.f)) {
              ps4[jj] += __expf(-2.f * (wsim - 0.5f)); ap4[jj] += 1.f;
            }
          } else {
            if (s + mg4[jj] - mnp[jj] > 0.f) {
              ns4[jj] += __expf(10.f * (wsim - 0.5f)); an4[jj] += 1.f;
            }
          }
        } else {
          if (same) {
            if (s < 1.0f) { ps4[jj] += __expf(-2.f * (s - 0.5f - mg4[jj])); ap4[jj] += 1.f; }
          } else {
            ns4[jj] += __expf(10.f * (s - 0.5f + mg4[jj])); an4[jj] += 1.f;
          }
        }
      }
    }
#pragma unroll
  for (int msk = 1; msk < 16; msk <<= 1)
#pragma unroll
    for (int jj = 0; jj < 4; ++jj) {
      ps4[jj] += __shfl_xor(ps4[jj], msk, 64);
      ns4[jj] += __shfl_xor(ns4[jj], msk, 64);
      ap4[jj] += __shfl_xor(ap4[jj], msk, 64);
      an4[jj] += __shfl_xor(an4[jj], msk, 64);
    }
  if (c == 0) {
#pragma unroll
    for (int jj = 0; jj < 4; ++jj) {
      int r = g * 4 + jj;
      redA[w][r] = ps4[jj]; redB[w][r] = ns4[jj];
      redC[w][r] = ap4[jj]; redD[w][r] = an4[jj];
    }
  }
  __syncthreads();
  if (tid < 16) {
    float ps = 0.f, ns = 0.f, ap = 0.f, an = 0.f;
#pragma unroll
    for (int w8 = 0; w8 < 8; ++w8) {
      ps += redA[w8][tid]; ns += redB[w8][tid];
      ap += redC[w8][tid]; an += redD[w8][tid];
    }
    float loss_i = 1.0f * log1pf(ps) + 0.2f * log1pf(ns);
    if (mode == 1 && (ap + an) < 1.0f) { loss_i = 0.f; ap = 0.f; an = 0.f; }
    out[1 + i0 + tid]     = ap;
    out[1 + N + i0 + tid] = an;
    lsRow[tid] = loss_i;
  }
  __syncthreads();
  if (tid == 0) {
    float lb = 0.f;
#pragma unroll
    for (int r = 0; r < 16; ++r) lb += lsRow[r];
    stg(&lpart[bid], lb);
    asm volatile("s_waitcnt vmcnt(0)" ::: "memory");
    unsigned o = __hip_atomic_fetch_add(done, 1u, __ATOMIC_ACQ_REL, __HIP_MEMORY_SCOPE_AGENT);
    lastf = (o == (unsigned)(NBLKS - 1)) ? 1u : 0u;
  }
  __syncthreads();

  // ---- last block deterministically sums the 256 loss partials ----
  if (lastf) {
    float v = (tid < NBLKS) ? ldg1(&lpart[tid]) : 0.f;
#pragma unroll
    for (int msk = 32; msk; msk >>= 1) v += __shfl_down(v, msk, 64);
    if ((tid & 63) == 0) lsum[tid >> 6] = v;
    __syncthreads();
    if (tid == 0) {
      float s = 0.f;
#pragma unroll
      for (int k2 = 0; k2 < 8; ++k2) s += lsum[k2];
      out[0] = s / (float)N;
    }
  }
}

extern "C" void kernel_launch(void* const* d_in, const int* in_sizes, int n_in,
                              void* d_out, int out_size, void* d_ws, size_t ws_size,
                              hipStream_t stream)
{
  (void)in_sizes; (void)n_in; (void)out_size; (void)ws_size;
  const float* x    = (const float*)d_in[0];
  const int*   tgt  = (const int*)d_in[1];
  const float* marg = (const float*)d_in[2];
  const float* wgt  = (const float*)d_in[3];
  const int*   hm   = (const int*)d_in[4];
  float* out = (float*)d_out;

  ushort*   xh    = (ushort*)d_ws;                          // 1 MB pre-swizzled bf16-hi
  float*    lpart = (float*)((char*)d_ws + (1 << 20));      // 256 loss partials
  unsigned* done  = (unsigned*)(lpart + NBLKS);             // 1 counter

  hipMemsetAsync(done, 0, sizeof(unsigned), stream);
  k_conv<<<256, 256, 0, stream>>>(x, xh);
  k_main<<<NBLKS, 512, 0, stream>>>(x, tgt, marg, wgt, hm, out, xh, lpart, done);
}

// Round 14
// 48.970 us; speedup vs baseline: 1.4278x; 1.1746x over previous
//
#include <hip/hip_runtime.h>
#include <math.h>

#define N 4096
#define D 128
#define NROW 16               // rows per block
#define NBLKS 256             // main-kernel grid (one 16-row panel per block)
#define BIGV 1e30f

typedef __bf16 bf16x8 __attribute__((ext_vector_type(8)));
typedef float  f32x4  __attribute__((ext_vector_type(4)));

__device__ __forceinline__ void stg(float* p, float v) {
  __hip_atomic_store(p, v, __ATOMIC_RELAXED, __HIP_MEMORY_SCOPE_AGENT);
}
__device__ __forceinline__ float ldg1(const float* p) {
  return __hip_atomic_load((float*)p, __ATOMIC_RELAXED, __HIP_MEMORY_SCOPE_AGENT);
}

// split 8 f32 -> 8 bf16 hi + 8 bf16 lo (rne/rne; proven bit-exact path)
__device__ __forceinline__ void cvt8(float4 v0, float4 v1, int4& hp, int4& lp) {
  float vf[8] = {v0.x, v0.y, v0.z, v0.w, v1.x, v1.y, v1.z, v1.w};
  unsigned h[8], l[8];
#pragma unroll
  for (int i = 0; i < 8; ++i) {
    unsigned u = __float_as_uint(vf[i]);
    unsigned hr = (u + 0x7FFFu + ((u >> 16) & 1u)) >> 16;
    float hv = __uint_as_float(hr << 16);
    unsigned ul = __float_as_uint(vf[i] - hv);
    l[i] = (ul + 0x7FFFu + ((ul >> 16) & 1u)) >> 16;
    h[i] = hr;
  }
  hp = make_int4((int)(h[0] | (h[1] << 16)), (int)(h[2] | (h[3] << 16)),
                 (int)(h[4] | (h[5] << 16)), (int)(h[6] | (h[7] << 16)));
  lp = make_int4((int)(l[0] | (l[1] << 16)), (int)(l[2] | (l[3] << 16)),
                 (int)(l[4] | (l[5] << 16)), (int)(l[6] | (l[7] << 16)));
}
__device__ __forceinline__ void cvt8hi(float4 v0, float4 v1, int4& hp) {
  float vf[8] = {v0.x, v0.y, v0.z, v0.w, v1.x, v1.y, v1.z, v1.w};
  unsigned h[8];
#pragma unroll
  for (int i = 0; i < 8; ++i) {
    unsigned u = __float_as_uint(vf[i]);
    h[i] = (u + 0x7FFFu + ((u >> 16) & 1u)) >> 16;
  }
  hp = make_int4((int)(h[0] | (h[1] << 16)), (int)(h[2] | (h[3] << 16)),
                 (int)(h[4] | (h[5] << 16)), (int)(h[6] | (h[7] << 16)));
}

// ---- convert kernel: x -> bf16-hi in MFMA-fragment-linear order ----
// For global "col" C (x-row) and k-element K: ct=C>>4, c=C&15, kt=K>>5,
// g=(K>>3)&3, e=K&7, lane=g*16+c. 16B unit index = (ct*4+kt)*64 + lane.
// One thread converts (C, k16): K = k16*8..k16*8+7 -> single int4 store.
__global__ __launch_bounds__(256)
void k_conv(const float* __restrict__ x, ushort* __restrict__ xf)
{
  int gid = blockIdx.x * 256 + threadIdx.x;     // 65536 = 4096 C x 16 k16
  int C = gid >> 4, k16 = gid & 15;
  const float* ap = x + C * D + k16 * 8;
  float4 v0 = *(const float4*)ap, v1 = *(const float4*)(ap + 4);
  int4 hp;
  cvt8hi(v0, v1, hp);
  int unit = ((C >> 4) * 4 + (k16 >> 2)) * 64 + (k16 & 3) * 16 + (C & 15);
  *(int4*)((char*)xf + ((size_t)unit << 4)) = hp;
}

__global__ __launch_bounds__(1024, 1)
void k_main(const float* __restrict__ x, const int* __restrict__ tgt,
            const float* __restrict__ marg, const float* __restrict__ wgt,
            const int* __restrict__ hm, float* __restrict__ out,
            const ushort* __restrict__ xf, float* __restrict__ lpart,
            unsigned* __restrict__ done)
{
  __shared__ float redA[16][16], redB[16][16], redC[16][16], redD[16][16];
  __shared__ float finMn[16], finMx[16], finMg[16], finWt[16], lsRow[16];
  __shared__ int   tgRow[16];
  __shared__ float lsum[4];
  __shared__ unsigned lastf;

  const int tid = threadIdx.x;
  const int bid = blockIdx.x;
  const int w = tid >> 6, l = tid & 63;     // 16 waves; wave w owns cols [w*256, w*256+256)
  const int c = l & 15, g = l >> 4;
  const int i0 = bid * NROW;

  if (tid < 16) {
    tgRow[tid] = tgt[i0 + tid];
    finMg[tid] = marg[i0 + tid];
    finWt[tid] = wgt[i0 + tid];
  }

  // ---- A fragments (16 rows, hi+lo) in registers: row i0+c, k = kt*32 + g*8 ----
  bf16x8 Ah[4], Al[4];
#pragma unroll
  for (int kt = 0; kt < 4; ++kt) {
    const float* ap = x + (i0 + c) * D + kt * 32 + g * 8;
    float4 v0 = *(const float4*)ap, v1 = *(const float4*)(ap + 4);
    int4 hp, lp;
    cvt8(v0, v1, hp, lp);
    Ah[kt] = *(bf16x8*)&hp;
    Al[kt] = *(bf16x8*)&lp;
  }

  f32x4 acc[16];
#pragma unroll
  for (int ci = 0; ci < 16; ++ci) acc[ci] = f32x4{0.f, 0.f, 0.f, 0.f};

  // ---- main loop: fragment-linear L2 streaming, fully coalesced 1KB wave loads ----
#pragma unroll
  for (int ci = 0; ci < 16; ++ci) {
    const int ct = (w << 4) + ci;
    if (ct == bid) {
      // diagonal tile: B-frags are the A-frag registers -> exact 3-product
#pragma unroll
      for (int kt = 0; kt < 4; ++kt) {
        acc[ci] = __builtin_amdgcn_mfma_f32_16x16x32_bf16(Ah[kt], Ah[kt], acc[ci], 0, 0, 0);
        acc[ci] = __builtin_amdgcn_mfma_f32_16x16x32_bf16(Ah[kt], Al[kt], acc[ci], 0, 0, 0);
        acc[ci] = __builtin_amdgcn_mfma_f32_16x16x32_bf16(Al[kt], Ah[kt], acc[ci], 0, 0, 0);
      }
    } else {
      const char* bp = (const char*)xf + (((size_t)ct * 256 + l) << 4);
#pragma unroll
      for (int kt = 0; kt < 4; ++kt) {
        bf16x8 Bh = *(const bf16x8*)(bp + (kt << 10));
        acc[ci] = __builtin_amdgcn_mfma_f32_16x16x32_bf16(Ah[kt], Bh, acc[ci], 0, 0, 0);
        acc[ci] = __builtin_amdgcn_mfma_f32_16x16x32_bf16(Al[kt], Bh, acc[ci], 0, 0, 0);
      }
    }
  }
  __syncthreads();   // tgRow/finMg/finWt ready; all compute done

  // ---- block-local min-pos / max-neg ----
  int trow[4];
  float mn4[4], mx4[4];
#pragma unroll
  for (int jj = 0; jj < 4; ++jj) {
    trow[jj] = tgRow[g * 4 + jj];
    mn4[jj] = BIGV; mx4[jj] = -BIGV;
  }
#pragma unroll
  for (int ci = 0; ci < 16; ++ci) {
    int cg = ((w << 4) + ci) * 16 + c;
    int tc = tgt[cg];
#pragma unroll
    for (int jj = 0; jj < 4; ++jj) {
      float s = acc[ci][jj];
      if (tc == trow[jj]) { if (s < 1.0f) mn4[jj] = fminf(mn4[jj], s); }
      else                  mx4[jj] = fmaxf(mx4[jj], s);
    }
  }
#pragma unroll
  for (int msk = 1; msk < 16; msk <<= 1)
#pragma unroll
    for (int jj = 0; jj < 4; ++jj) {
      mn4[jj] = fminf(mn4[jj], __shfl_xor(mn4[jj], msk, 64));
      mx4[jj] = fmaxf(mx4[jj], __shfl_xor(mx4[jj], msk, 64));
    }
  if (c == 0) {
#pragma unroll
    for (int jj = 0; jj < 4; ++jj) {
      redA[w][g * 4 + jj] = mn4[jj];
      redB[w][g * 4 + jj] = mx4[jj];
    }
  }
  __syncthreads();
  if (tid < 16) {
    float mn = BIGV, mx = -BIGV;
#pragma unroll
    for (int w16 = 0; w16 < 16; ++w16) {
      mn = fminf(mn, redA[w16][tid]);
      mx = fmaxf(mx, redB[w16][tid]);
    }
    finMn[tid] = mn; finMx[tid] = mx;
  }
  __syncthreads();

  // ---- mining epilogue over the same in-register acc ----
  const int mode = hm[0];
  float mnp[4], mxn[4], mg4[4], wt4[4];
  float ps4[4], ns4[4], ap4[4], an4[4];
#pragma unroll
  for (int jj = 0; jj < 4; ++jj) {
    int r = g * 4 + jj;
    mnp[jj] = finMn[r]; mxn[jj] = finMx[r]; mg4[jj] = finMg[r]; wt4[jj] = finWt[r];
    ps4[jj] = 0.f; ns4[jj] = 0.f; ap4[jj] = 0.f; an4[jj] = 0.f;
  }
#pragma unroll
  for (int ci = 0; ci < 16; ++ci) {
    int cg = ((w << 4) + ci) * 16 + c;
    int tc = tgt[cg];
#pragma unroll
    for (int jj = 0; jj < 4; ++jj) {
      float s = acc[ci][jj];
      bool same = (tc == trow[jj]);
      if (mode == 1) {
        float wsim = s * wt4[jj];
        if (same) {
          if (s < 1.0f && (mxn[jj] - s + mg4[jj] > 0.f)) {
            ps4[jj] += __expf(-2.f * (wsim - 0.5f)); ap4[jj] += 1.f;
          }
        } else {
          if (s + mg4[jj] - mnp[jj] > 0.f) {
            ns4[jj] += __expf(10.f * (wsim - 0.5f)); an4[jj] += 1.f;
          }
        }
      } else {
        if (same) {
          if (s < 1.0f) { ps4[jj] += __expf(-2.f * (s - 0.5f - mg4[jj])); ap4[jj] += 1.f; }
        } else {
          ns4[jj] += __expf(10.f * (s - 0.5f + mg4[jj])); an4[jj] += 1.f;
        }
      }
    }
  }
#pragma unroll
  for (int msk = 1; msk < 16; msk <<= 1)
#pragma unroll
    for (int jj = 0; jj < 4; ++jj) {
      ps4[jj] += __shfl_xor(ps4[jj], msk, 64);
      ns4[jj] += __shfl_xor(ns4[jj], msk, 64);
      ap4[jj] += __shfl_xor(ap4[jj], msk, 64);
      an4[jj] += __shfl_xor(an4[jj], msk, 64);
    }
  if (c == 0) {
#pragma unroll
    for (int jj = 0; jj < 4; ++jj) {
      int r = g * 4 + jj;
      redA[w][r] = ps4[jj]; redB[w][r] = ns4[jj];
      redC[w][r] = ap4[jj]; redD[w][r] = an4[jj];
    }
  }
  __syncthreads();
  if (tid < 16) {
    float ps = 0.f, ns = 0.f, ap = 0.f, an = 0.f;
#pragma unroll
    for (int w16 = 0; w16 < 16; ++w16) {
      ps += redA[w16][tid]; ns += redB[w16][tid];
      ap += redC[w16][tid]; an += redD[w16][tid];
    }
    float loss_i = 1.0f * log1pf(ps) + 0.2f * log1pf(ns);
    if (mode == 1 && (ap + an) < 1.0f) { loss_i = 0.f; ap = 0.f; an = 0.f; }
    out[1 + i0 + tid]     = ap;
    out[1 + N + i0 + tid] = an;
    lsRow[tid] = loss_i;
  }
  __syncthreads();
  if (tid == 0) {
    float lb = 0.f;
#pragma unroll
    for (int r = 0; r < 16; ++r) lb += lsRow[r];
    stg(&lpart[bid], lb);
    asm volatile("s_waitcnt vmcnt(0)" ::: "memory");
    unsigned o = __hip_atomic_fetch_add(done, 1u, __ATOMIC_ACQ_REL, __HIP_MEMORY_SCOPE_AGENT);
    lastf = (o == (unsigned)(NBLKS - 1)) ? 1u : 0u;
  }
  __syncthreads();

  // ---- last block deterministically sums the 256 loss partials ----
  if (lastf) {
    float v = (tid < NBLKS) ? ldg1(&lpart[tid]) : 0.f;
#pragma unroll
    for (int msk = 32; msk; msk >>= 1) v += __shfl_down(v, msk, 64);
    if (tid < NBLKS && (tid & 63) == 0) lsum[tid >> 6] = v;
    __syncthreads();
    if (tid == 0) {
      float s = 0.f;
#pragma unroll
      for (int k2 = 0; k2 < 4; ++k2) s += lsum[k2];
      out[0] = s / (float)N;
    }
  }
}

extern "C" void kernel_launch(void* const* d_in, const int* in_sizes, int n_in,
                              void* d_out, int out_size, void* d_ws, size_t ws_size,
                              hipStream_t stream)
{
  (void)in_sizes; (void)n_in; (void)out_size; (void)ws_size;
  const float* x    = (const float*)d_in[0];
  const int*   tgt  = (const int*)d_in[1];
  const float* marg = (const float*)d_in[2];
  const float* wgt  = (const float*)d_in[3];
  const int*   hm   = (const int*)d_in[4];
  float* out = (float*)d_out;

  ushort*   xf    = (ushort*)d_ws;                          // 1 MB fragment-linear bf16-hi
  float*    lpart = (float*)((char*)d_ws + (1 << 20));      // 256 loss partials
  unsigned* done  = (unsigned*)(lpart + NBLKS);             // 1 counter

  hipMemsetAsync(done, 0, sizeof(unsigned), stream);
  k_conv<<<256, 256, 0, stream>>>(x, xf);
  k_main<<<NBLKS, 1024, 0, stream>>>(x, tgt, marg, wgt, hm, out, xf, lpart, done);
}

// Round 15
// 46.035 us; speedup vs baseline: 1.5188x; 1.0638x over previous
//
#include <hip/hip_runtime.h>
#include <math.h>

#define N 4096
#define D 128
#define NROW 16               // rows per block
#define NBLKS 256             // main-kernel grid (one 16-row panel per block)
#define BIGV 1e30f

typedef __bf16 bf16x8 __attribute__((ext_vector_type(8)));
typedef float  f32x4  __attribute__((ext_vector_type(4)));
typedef __attribute__((address_space(3))) unsigned lds_u32;
typedef const __attribute__((address_space(1))) unsigned glb_u32;

__device__ __forceinline__ void stg(float* p, float v) {
  __hip_atomic_store(p, v, __ATOMIC_RELAXED, __HIP_MEMORY_SCOPE_AGENT);
}
__device__ __forceinline__ float ldg1(const float* p) {
  return __hip_atomic_load((float*)p, __ATOMIC_RELAXED, __HIP_MEMORY_SCOPE_AGENT);
}

// split 8 f32 -> 8 bf16 hi + 8 bf16 lo (rne/rne; proven bit-exact path)
__device__ __forceinline__ void cvt8(float4 v0, float4 v1, int4& hp, int4& lp) {
  float vf[8] = {v0.x, v0.y, v0.z, v0.w, v1.x, v1.y, v1.z, v1.w};
  unsigned h[8], l[8];
#pragma unroll
  for (int i = 0; i < 8; ++i) {
    unsigned u = __float_as_uint(vf[i]);
    unsigned hr = (u + 0x7FFFu + ((u >> 16) & 1u)) >> 16;
    float hv = __uint_as_float(hr << 16);
    unsigned ul = __float_as_uint(vf[i] - hv);
    l[i] = (ul + 0x7FFFu + ((ul >> 16) & 1u)) >> 16;
    h[i] = hr;
  }
  hp = make_int4((int)(h[0] | (h[1] << 16)), (int)(h[2] | (h[3] << 16)),
                 (int)(h[4] | (h[5] << 16)), (int)(h[6] | (h[7] << 16)));
  lp = make_int4((int)(l[0] | (l[1] << 16)), (int)(l[2] | (l[3] << 16)),
                 (int)(l[4] | (l[5] << 16)), (int)(l[6] | (l[7] << 16)));
}
__device__ __forceinline__ void cvt8hi(float4 v0, float4 v1, int4& hp) {
  float vf[8] = {v0.x, v0.y, v0.z, v0.w, v1.x, v1.y, v1.z, v1.w};
  unsigned h[8];
#pragma unroll
  for (int i = 0; i < 8; ++i) {
    unsigned u = __float_as_uint(vf[i]);
    h[i] = (u + 0x7FFFu + ((u >> 16) & 1u)) >> 16;
  }
  hp = make_int4((int)(h[0] | (h[1] << 16)), (int)(h[2] | (h[3] << 16)),
                 (int)(h[4] | (h[5] << 16)), (int)(h[6] | (h[7] << 16)));
}

// ---- convert kernel: x -> bf16-hi in MFMA-fragment-linear order ----
// byte offset for (col C, k16) = C>>4)*4096 ... : unit = ((C>>4)*4 + (k16>>2))*64
//   + (k16&3)*16 + (C&15); each 16B unit is one lane's ds/global fragment slice.
// Also resets the done-counter (replaces a separate memset dispatch).
__global__ __launch_bounds__(256)
void k_conv(const float* __restrict__ x, ushort* __restrict__ xf, unsigned* done)
{
  if (blockIdx.x == 0 && threadIdx.x == 0)
    __hip_atomic_store(done, 0u, __ATOMIC_RELAXED, __HIP_MEMORY_SCOPE_AGENT);
  int gid = blockIdx.x * 256 + threadIdx.x;     // 65536 = 4096 C x 16 k16
  int C = gid >> 4, k16 = gid & 15;
  const float* ap = x + C * D + k16 * 8;
  float4 v0 = *(const float4*)ap, v1 = *(const float4*)(ap + 4);
  int4 hp;
  cvt8hi(v0, v1, hp);
  int unit = ((C >> 4) * 4 + (k16 >> 2)) * 64 + (k16 & 3) * 16 + (C & 15);
  *(int4*)((char*)xf + ((size_t)unit << 4)) = hp;
}

#define VMCNT(n) asm volatile("s_waitcnt vmcnt(" #n ")" ::: "memory")

// stage tile ct_ (4 KB: 4 kt x 64 lanes x 16B) into wave-private buffer b_
#define STAGE(b_, ct_) do {                                                        \
    const char* gsrc_ = (const char*)xf + ((size_t)(ct_) << 12) + (l << 4);        \
    char* ldst_ = bbase + ((b_) << 12);                                            \
    _Pragma("unroll")                                                              \
    for (int kt_ = 0; kt_ < 4; ++kt_)                                              \
      __builtin_amdgcn_global_load_lds((glb_u32*)(gsrc_ + (kt_ << 10)),            \
                                       (lds_u32*)(ldst_ + (kt_ << 10)), 16, 0, 0); \
  } while (0)

__global__ __launch_bounds__(1024, 1)
void k_main(const float* __restrict__ x, const int* __restrict__ tgt,
            const float* __restrict__ marg, const float* __restrict__ wgt,
            const int* __restrict__ hm, float* __restrict__ out,
            const ushort* __restrict__ xf, float* __restrict__ lpart,
            unsigned* __restrict__ done)
{
  __shared__ __bf16 Bbuf[16][2][2048];          // 16 waves x 2 x 4 KB = 128 KB
  __shared__ float redA[16][16], redB[16][16], redC[16][16], redD[16][16];
  __shared__ float finMn[16], finMx[16], finMg[16], finWt[16], lsRow[16];
  __shared__ int   tgRow[16];
  __shared__ float lsum[4];
  __shared__ unsigned lastf;

  const int tid = threadIdx.x;
  const int bid = blockIdx.x;
  const int w = tid >> 6, l = tid & 63;     // 16 waves; wave w owns cols [w*256, w*256+256)
  const int c = l & 15, g = l >> 4;
  const int i0 = bid * NROW;
  char* bbase = (char*)&Bbuf[w][0][0];

  if (tid < 16) {
    tgRow[tid] = tgt[i0 + tid];
    finMg[tid] = marg[i0 + tid];
    finWt[tid] = wgt[i0 + tid];
  }

  // ---- A fragments (16 rows, hi+lo) in registers: row i0+c, k = kt*32 + g*8 ----
  bf16x8 Ah[4], Al[4];
#pragma unroll
  for (int kt = 0; kt < 4; ++kt) {
    const float* ap = x + (i0 + c) * D + kt * 32 + g * 8;
    float4 v0 = *(const float4*)ap, v1 = *(const float4*)(ap + 4);
    int4 hp, lp;
    cvt8(v0, v1, hp, lp);
    Ah[kt] = *(bf16x8*)&hp;
    Al[kt] = *(bf16x8*)&lp;
  }

  f32x4 acc[16];
#pragma unroll
  for (int ci = 0; ci < 16; ++ci) acc[ci] = f32x4{0.f, 0.f, 0.f, 0.f};

  // ---- K-loop: wave-private LDS double-buffer, counted vmcnt, no barriers ----
  STAGE(0, (w << 4));
#pragma unroll
  for (int ci = 0; ci < 16; ++ci) {
    __builtin_amdgcn_sched_barrier(0);
    if (ci + 1 < 16) {
      STAGE((ci + 1) & 1, (w << 4) + ci + 1);
      VMCNT(4);                 // tile ci ready; ci+1's 4 loads stay in flight
    } else {
      VMCNT(0);
    }
    __builtin_amdgcn_sched_barrier(0);
    const int ct = (w << 4) + ci;
    if (ct == bid) {
      // diagonal tile: B-frags are the A-frag registers -> exact 3-product
#pragma unroll
      for (int kt = 0; kt < 4; ++kt) {
        acc[ci] = __builtin_amdgcn_mfma_f32_16x16x32_bf16(Ah[kt], Ah[kt], acc[ci], 0, 0, 0);
        acc[ci] = __builtin_amdgcn_mfma_f32_16x16x32_bf16(Ah[kt], Al[kt], acc[ci], 0, 0, 0);
        acc[ci] = __builtin_amdgcn_mfma_f32_16x16x32_bf16(Al[kt], Ah[kt], acc[ci], 0, 0, 0);
      }
    } else {
      const char* bp = bbase + ((ci & 1) << 12) + (l << 4);
#pragma unroll
      for (int kt = 0; kt < 4; ++kt) {
        bf16x8 Bh = *(const bf16x8*)(bp + (kt << 10));
        acc[ci] = __builtin_amdgcn_mfma_f32_16x16x32_bf16(Ah[kt], Bh, acc[ci], 0, 0, 0);
        acc[ci] = __builtin_amdgcn_mfma_f32_16x16x32_bf16(Al[kt], Bh, acc[ci], 0, 0, 0);
      }
    }
  }
  __syncthreads();   // tgRow/finMg/finWt ready; all compute done

  // ---- block-local min-pos / max-neg ----
  int trow[4];
  float mn4[4], mx4[4];
#pragma unroll
  for (int jj = 0; jj < 4; ++jj) {
    trow[jj] = tgRow[g * 4 + jj];
    mn4[jj] = BIGV; mx4[jj] = -BIGV;
  }
#pragma unroll
  for (int ci = 0; ci < 16; ++ci) {
    int cg = ((w << 4) + ci) * 16 + c;
    int tc = tgt[cg];
#pragma unroll
    for (int jj = 0; jj < 4; ++jj) {
      float s = acc[ci][jj];
      if (tc == trow[jj]) { if (s < 1.0f) mn4[jj] = fminf(mn4[jj], s); }
      else                  mx4[jj] = fmaxf(mx4[jj], s);
    }
  }
#pragma unroll
  for (int msk = 1; msk < 16; msk <<= 1)
#pragma unroll
    for (int jj = 0; jj < 4; ++jj) {
      mn4[jj] = fminf(mn4[jj], __shfl_xor(mn4[jj], msk, 64));
      mx4[jj] = fmaxf(mx4[jj], __shfl_xor(mx4[jj], msk, 64));
    }
  if (c == 0) {
#pragma unroll
    for (int jj = 0; jj < 4; ++jj) {
      redA[w][g * 4 + jj] = mn4[jj];
      redB[w][g * 4 + jj] = mx4[jj];
    }
  }
  __syncthreads();
  if (tid < 16) {
    float mn = BIGV, mx = -BIGV;
#pragma unroll
    for (int w16 = 0; w16 < 16; ++w16) {
      mn = fminf(mn, redA[w16][tid]);
      mx = fmaxf(mx, redB[w16][tid]);
    }
    finMn[tid] = mn; finMx[tid] = mx;
  }
  __syncthreads();

  // ---- mining epilogue over the same in-register acc ----
  const int mode = hm[0];
  float mnp[4], mxn[4], mg4[4], wt4[4];
  float ps4[4], ns4[4], ap4[4], an4[4];
#pragma unroll
  for (int jj = 0; jj < 4; ++jj) {
    int r = g * 4 + jj;
    mnp[jj] = finMn[r]; mxn[jj] = finMx[r]; mg4[jj] = finMg[r]; wt4[jj] = finWt[r];
    ps4[jj] = 0.f; ns4[jj] = 0.f; ap4[jj] = 0.f; an4[jj] = 0.f;
  }
#pragma unroll
  for (int ci = 0; ci < 16; ++ci) {
    int cg = ((w << 4) + ci) * 16 + c;
    int tc = tgt[cg];
#pragma unroll
    for (int jj = 0; jj < 4; ++jj) {
      float s = acc[ci][jj];
      bool same = (tc == trow[jj]);
      if (mode == 1) {
        float wsim = s * wt4[jj];
        if (same) {
          if (s < 1.0f && (mxn[jj] - s + mg4[jj] > 0.f)) {
            ps4[jj] += __expf(-2.f * (wsim - 0.5f)); ap4[jj] += 1.f;
          }
        } else {
          if (s + mg4[jj] - mnp[jj] > 0.f) {
            ns4[jj] += __expf(10.f * (wsim - 0.5f)); an4[jj] += 1.f;
          }
        }
      } else {
        if (same) {
          if (s < 1.0f) { ps4[jj] += __expf(-2.f * (s - 0.5f - mg4[jj])); ap4[jj] += 1.f; }
        } else {
          ns4[jj] += __expf(10.f * (s - 0.5f + mg4[jj])); an4[jj] += 1.f;
        }
      }
    }
  }
#pragma unroll
  for (int msk = 1; msk < 16; msk <<= 1)
#pragma unroll
    for (int jj = 0; jj < 4; ++jj) {
      ps4[jj] += __shfl_xor(ps4[jj], msk, 64);
      ns4[jj] += __shfl_xor(ns4[jj], msk, 64);
      ap4[jj] += __shfl_xor(ap4[jj], msk, 64);
      an4[jj] += __shfl_xor(an4[jj], msk, 64);
    }
  if (c == 0) {
#pragma unroll
    for (int jj = 0; jj < 4; ++jj) {
      int r = g * 4 + jj;
      redA[w][r] = ps4[jj]; redB[w][r] = ns4[jj];
      redC[w][r] = ap4[jj]; redD[w][r] = an4[jj];
    }
  }
  __syncthreads();
  if (tid < 16) {
    float ps = 0.f, ns = 0.f, ap = 0.f, an = 0.f;
#pragma unroll
    for (int w16 = 0; w16 < 16; ++w16) {
      ps += redA[w16][tid]; ns += redB[w16][tid];
      ap += redC[w16][tid]; an += redD[w16][tid];
    }
    float loss_i = 1.0f * log1pf(ps) + 0.2f * log1pf(ns);
    if (mode == 1 && (ap + an) < 1.0f) { loss_i = 0.f; ap = 0.f; an = 0.f; }
    out[1 + i0 + tid]     = ap;
    out[1 + N + i0 + tid] = an;
    lsRow[tid] = loss_i;
  }
  __syncthreads();
  if (tid == 0) {
    float lb = 0.f;
#pragma unroll
    for (int r = 0; r < 16; ++r) lb += lsRow[r];
    stg(&lpart[bid], lb);
    asm volatile("s_waitcnt vmcnt(0)" ::: "memory");
    unsigned o = __hip_atomic_fetch_add(done, 1u, __ATOMIC_ACQ_REL, __HIP_MEMORY_SCOPE_AGENT);
    lastf = (o == (unsigned)(NBLKS - 1)) ? 1u : 0u;
  }
  __syncthreads();

  // ---- last block deterministically sums the 256 loss partials ----
  if (lastf) {
    float v = (tid < NBLKS) ? ldg1(&lpart[tid]) : 0.f;
#pragma unroll
    for (int msk = 32; msk; msk >>= 1) v += __shfl_down(v, msk, 64);
    if (tid < NBLKS && (tid & 63) == 0) lsum[tid >> 6] = v;
    __syncthreads();
    if (tid == 0) {
      float s = 0.f;
#pragma unroll
      for (int k2 = 0; k2 < 4; ++k2) s += lsum[k2];
      out[0] = s / (float)N;
    }
  }
}

extern "C" void kernel_launch(void* const* d_in, const int* in_sizes, int n_in,
                              void* d_out, int out_size, void* d_ws, size_t ws_size,
                              hipStream_t stream)
{
  (void)in_sizes; (void)n_in; (void)out_size; (void)ws_size;
  const float* x    = (const float*)d_in[0];
  const int*   tgt  = (const int*)d_in[1];
  const float* marg = (const float*)d_in[2];
  const float* wgt  = (const float*)d_in[3];
  const int*   hm   = (const int*)d_in[4];
  float* out = (float*)d_out;

  ushort*   xf    = (ushort*)d_ws;                          // 1 MB fragment-linear bf16-hi
  float*    lpart = (float*)((char*)d_ws + (1 << 20));      // 256 loss partials
  unsigned* done  = (unsigned*)(lpart + NBLKS);             // 1 counter

  k_conv<<<256, 256, 0, stream>>>(x, xf, done);
  k_main<<<NBLKS, 1024, 0, stream>>>(x, tgt, marg, wgt, hm, out, xf, lpart, done);
}

// Round 16
// 43.408 us; speedup vs baseline: 1.6107x; 1.0605x over previous
//
#include <hip/hip_runtime.h>
#include <math.h>

#define N 4096
#define D 128
#define NROW 16               // rows per block
#define NBLKS 256             // main-kernel grid (one 16-row panel per block)
#define BIGV 1e30f

typedef __bf16 bf16x8 __attribute__((ext_vector_type(8)));
typedef float  f32x4  __attribute__((ext_vector_type(4)));
typedef __attribute__((address_space(3))) unsigned lds_u32;
typedef const __attribute__((address_space(1))) unsigned glb_u32;

__device__ __forceinline__ void stg(float* p, float v) {
  __hip_atomic_store(p, v, __ATOMIC_RELAXED, __HIP_MEMORY_SCOPE_AGENT);
}
__device__ __forceinline__ float ldg1(const float* p) {
  return __hip_atomic_load((float*)p, __ATOMIC_RELAXED, __HIP_MEMORY_SCOPE_AGENT);
}

// split 8 f32 -> 8 bf16 hi + 8 bf16 lo (rne/rne; proven bit-exact path)
__device__ __forceinline__ void cvt8(float4 v0, float4 v1, int4& hp, int4& lp) {
  float vf[8] = {v0.x, v0.y, v0.z, v0.w, v1.x, v1.y, v1.z, v1.w};
  unsigned h[8], l[8];
#pragma unroll
  for (int i = 0; i < 8; ++i) {
    unsigned u = __float_as_uint(vf[i]);
    unsigned hr = (u + 0x7FFFu + ((u >> 16) & 1u)) >> 16;
    float hv = __uint_as_float(hr << 16);
    unsigned ul = __float_as_uint(vf[i] - hv);
    l[i] = (ul + 0x7FFFu + ((ul >> 16) & 1u)) >> 16;
    h[i] = hr;
  }
  hp = make_int4((int)(h[0] | (h[1] << 16)), (int)(h[2] | (h[3] << 16)),
                 (int)(h[4] | (h[5] << 16)), (int)(h[6] | (h[7] << 16)));
  lp = make_int4((int)(l[0] | (l[1] << 16)), (int)(l[2] | (l[3] << 16)),
                 (int)(l[4] | (l[5] << 16)), (int)(l[6] | (l[7] << 16)));
}
__device__ __forceinline__ void cvt8hi(float4 v0, float4 v1, int4& hp) {
  float vf[8] = {v0.x, v0.y, v0.z, v0.w, v1.x, v1.y, v1.z, v1.w};
  unsigned h[8];
#pragma unroll
  for (int i = 0; i < 8; ++i) {
    unsigned u = __float_as_uint(vf[i]);
    h[i] = (u + 0x7FFFu + ((u >> 16) & 1u)) >> 16;
  }
  hp = make_int4((int)(h[0] | (h[1] << 16)), (int)(h[2] | (h[3] << 16)),
                 (int)(h[4] | (h[5] << 16)), (int)(h[6] | (h[7] << 16)));
}

// ---- convert kernel: x -> bf16-hi in MFMA-fragment-linear order ----
// unit = ((C>>4)*4 + (k16>>2))*64 + (k16&3)*16 + (C&15); 16B per unit.
// Also resets the done-counter (replaces a separate memset dispatch).
__global__ __launch_bounds__(256)
void k_conv(const float* __restrict__ x, ushort* __restrict__ xf, unsigned* done)
{
  if (blockIdx.x == 0 && threadIdx.x == 0)
    __hip_atomic_store(done, 0u, __ATOMIC_RELAXED, __HIP_MEMORY_SCOPE_AGENT);
  int gid = blockIdx.x * 256 + threadIdx.x;     // 65536 = 4096 C x 16 k16
  int C = gid >> 4, k16 = gid & 15;
  const float* ap = x + C * D + k16 * 8;
  float4 v0 = *(const float4*)ap, v1 = *(const float4*)(ap + 4);
  int4 hp;
  cvt8hi(v0, v1, hp);
  int unit = ((C >> 4) * 4 + (k16 >> 2)) * 64 + (k16 & 3) * 16 + (C & 15);
  *(int4*)((char*)xf + ((size_t)unit << 4)) = hp;
}

#define VMCNT(n) asm volatile("s_waitcnt vmcnt(" #n ")" ::: "memory")

// stage tile ct_ (4 KB: 4 kt x 64 lanes x 16B) into wave-private buffer b_
#define STAGE(b_, ct_) do {                                                        \
    const char* gsrc_ = (const char*)xf + ((size_t)(ct_) << 12) + (l << 4);        \
    char* ldst_ = bbase + ((b_) << 12);                                            \
    _Pragma("unroll")                                                              \
    for (int kt_ = 0; kt_ < 4; ++kt_)                                              \
      __builtin_amdgcn_global_load_lds((glb_u32*)(gsrc_ + (kt_ << 10)),            \
                                       (lds_u32*)(ldst_ + (kt_ << 10)), 16, 0, 0); \
  } while (0)

__global__ __launch_bounds__(1024, 1)
void k_main(const float* __restrict__ x, const int* __restrict__ tgt,
            const float* __restrict__ marg, const float* __restrict__ wgt,
            const int* __restrict__ hm, float* __restrict__ out,
            const ushort* __restrict__ xf, float* __restrict__ lpart,
            unsigned* __restrict__ done)
{
  __shared__ __bf16 Bbuf[16][2][2048];          // 16 waves x 2 x 4 KB = 128 KB
  __shared__ float redA[16][16], redB[16][16], redC[16][16], redD[16][16];
  __shared__ float finMn[16], finMx[16], lsRow[16];
  __shared__ float lsum[4];
  __shared__ unsigned lastf;

  const int tid = threadIdx.x;
  const int bid = blockIdx.x;
  const int w = tid >> 6, l = tid & 63;     // 16 waves; wave w owns cols [w*256, w*256+256)
  const int c = l & 15, g = l >> 4;
  const int i0 = bid * NROW;
  char* bbase = (char*)&Bbuf[w][0][0];

  // per-thread row metadata (direct global; lanes with equal g broadcast-coalesce)
  int trow[4];
#pragma unroll
  for (int jj = 0; jj < 4; ++jj) trow[jj] = tgt[i0 + g * 4 + jj];

  // ---- A fragments (16 rows, hi+lo) in registers: row i0+c, k = kt*32 + g*8 ----
  bf16x8 Ah[4], Al[4];
#pragma unroll
  for (int kt = 0; kt < 4; ++kt) {
    const float* ap = x + (i0 + c) * D + kt * 32 + g * 8;
    float4 v0 = *(const float4*)ap, v1 = *(const float4*)(ap + 4);
    int4 hp, lp;
    cvt8(v0, v1, hp, lp);
    Ah[kt] = *(bf16x8*)&hp;
    Al[kt] = *(bf16x8*)&lp;
  }

  f32x4 acc[16];
#pragma unroll
  for (int ci = 0; ci < 16; ++ci) acc[ci] = f32x4{0.f, 0.f, 0.f, 0.f};

  float mn4[4], mx4[4];
#pragma unroll
  for (int jj = 0; jj < 4; ++jj) { mn4[jj] = BIGV; mx4[jj] = -BIGV; }

  // ---- K-loop: LDS dbuf + counted vmcnt(5) (4 stage + 1 tgt per tile), no barriers.
  //      Pass-1 (min/max scan) FUSED after each tile's MFMAs -> fills staging stalls.
  STAGE(0, (w << 4));
  int tc_next = tgt[(w << 4) * 16 + c];
#pragma unroll
  for (int ci = 0; ci < 16; ++ci) {
    const int tc_cur = tc_next;
    __builtin_amdgcn_sched_barrier(0);
    if (ci + 1 < 16) {
      STAGE((ci + 1) & 1, (w << 4) + ci + 1);
      tc_next = tgt[((w << 4) + ci + 1) * 16 + c];
      __builtin_amdgcn_sched_barrier(0);
      VMCNT(5);                 // drains tile ci's 4 stages + tc_cur; next 5 in flight
    } else {
      __builtin_amdgcn_sched_barrier(0);
      VMCNT(0);
    }
    __builtin_amdgcn_sched_barrier(0);
    const int ct = (w << 4) + ci;
    if (ct == bid) {
      // diagonal tile: B-frags are the A-frag registers -> exact 3-product
#pragma unroll
      for (int kt = 0; kt < 4; ++kt) {
        acc[ci] = __builtin_amdgcn_mfma_f32_16x16x32_bf16(Ah[kt], Ah[kt], acc[ci], 0, 0, 0);
        acc[ci] = __builtin_amdgcn_mfma_f32_16x16x32_bf16(Ah[kt], Al[kt], acc[ci], 0, 0, 0);
        acc[ci] = __builtin_amdgcn_mfma_f32_16x16x32_bf16(Al[kt], Ah[kt], acc[ci], 0, 0, 0);
      }
    } else {
      const char* bp = bbase + ((ci & 1) << 12) + (l << 4);
#pragma unroll
      for (int kt = 0; kt < 4; ++kt) {
        bf16x8 Bh = *(const bf16x8*)(bp + (kt << 10));
        acc[ci] = __builtin_amdgcn_mfma_f32_16x16x32_bf16(Ah[kt], Bh, acc[ci], 0, 0, 0);
        acc[ci] = __builtin_amdgcn_mfma_f32_16x16x32_bf16(Al[kt], Bh, acc[ci], 0, 0, 0);
      }
    }
    // fused pass-1: acc[ci] is final for this tile
#pragma unroll
    for (int jj = 0; jj < 4; ++jj) {
      float s = acc[ci][jj];
      if (tc_cur == trow[jj]) { if (s < 1.0f) mn4[jj] = fminf(mn4[jj], s); }
      else                      mx4[jj] = fmaxf(mx4[jj], s);
    }
  }

  // ---- cross-lane + cross-wave min/max reduction ----
#pragma unroll
  for (int msk = 1; msk < 16; msk <<= 1)
#pragma unroll
    for (int jj = 0; jj < 4; ++jj) {
      mn4[jj] = fminf(mn4[jj], __shfl_xor(mn4[jj], msk, 64));
      mx4[jj] = fmaxf(mx4[jj], __shfl_xor(mx4[jj], msk, 64));
    }
  if (c == 0) {
#pragma unroll
    for (int jj = 0; jj < 4; ++jj) {
      redA[w][g * 4 + jj] = mn4[jj];
      redB[w][g * 4 + jj] = mx4[jj];
    }
  }
  __syncthreads();
  if (tid < 16) {
    float mn = BIGV, mx = -BIGV;
#pragma unroll
    for (int w16 = 0; w16 < 16; ++w16) {
      mn = fminf(mn, redA[w16][tid]);
      mx = fmaxf(mx, redB[w16][tid]);
    }
    finMn[tid] = mn; finMx[tid] = mx;
  }
  __syncthreads();

  // ---- mining epilogue over the same in-register acc ----
  const int mode = hm[0];
  float mnp[4], mxn[4], mg4[4], wt4[4];
  float ps4[4], ns4[4], ap4[4], an4[4];
#pragma unroll
  for (int jj = 0; jj < 4; ++jj) {
    int r = g * 4 + jj;
    mnp[jj] = finMn[r]; mxn[jj] = finMx[r];
    mg4[jj] = marg[i0 + r]; wt4[jj] = wgt[i0 + r];
    ps4[jj] = 0.f; ns4[jj] = 0.f; ap4[jj] = 0.f; an4[jj] = 0.f;
  }
#pragma unroll
  for (int ci = 0; ci < 16; ++ci) {
    int tc = tgt[((w << 4) + ci) * 16 + c];    // L1-hot (touched in K-loop)
#pragma unroll
    for (int jj = 0; jj < 4; ++jj) {
      float s = acc[ci][jj];
      bool same = (tc == trow[jj]);
      if (mode == 1) {
        float wsim = s * wt4[jj];
        if (same) {
          if (s < 1.0f && (mxn[jj] - s + mg4[jj] > 0.f)) {
            ps4[jj] += __expf(-2.f * (wsim - 0.5f)); ap4[jj] += 1.f;
          }
        } else {
          if (s + mg4[jj] - mnp[jj] > 0.f) {
            ns4[jj] += __expf(10.f * (wsim - 0.5f)); an4[jj] += 1.f;
          }
        }
      } else {
        if (same) {
          if (s < 1.0f) { ps4[jj] += __expf(-2.f * (s - 0.5f - mg4[jj])); ap4[jj] += 1.f; }
        } else {
          ns4[jj] += __expf(10.f * (s - 0.5f + mg4[jj])); an4[jj] += 1.f;
        }
      }
    }
  }
#pragma unroll
  for (int msk = 1; msk < 16; msk <<= 1)
#pragma unroll
    for (int jj = 0; jj < 4; ++jj) {
      ps4[jj] += __shfl_xor(ps4[jj], msk, 64);
      ns4[jj] += __shfl_xor(ns4[jj], msk, 64);
      ap4[jj] += __shfl_xor(ap4[jj], msk, 64);
      an4[jj] += __shfl_xor(an4[jj], msk, 64);
    }
  if (c == 0) {
#pragma unroll
    for (int jj = 0; jj < 4; ++jj) {
      int r = g * 4 + jj;
      redA[w][r] = ps4[jj]; redB[w][r] = ns4[jj];
      redC[w][r] = ap4[jj]; redD[w][r] = an4[jj];
    }
  }
  __syncthreads();
  if (tid < 16) {
    float ps = 0.f, ns = 0.f, ap = 0.f, an = 0.f;
#pragma unroll
    for (int w16 = 0; w16 < 16; ++w16) {
      ps += redA[w16][tid]; ns += redB[w16][tid];
      ap += redC[w16][tid]; an += redD[w16][tid];
    }
    float loss_i = 1.0f * log1pf(ps) + 0.2f * log1pf(ns);
    if (mode == 1 && (ap + an) < 1.0f) { loss_i = 0.f; ap = 0.f; an = 0.f; }
    out[1 + i0 + tid]     = ap;
    out[1 + N + i0 + tid] = an;
    lsRow[tid] = loss_i;
  }
  __syncthreads();
  if (tid == 0) {
    float lb = 0.f;
#pragma unroll
    for (int r = 0; r < 16; ++r) lb += lsRow[r];
    stg(&lpart[bid], lb);
    asm volatile("s_waitcnt vmcnt(0)" ::: "memory");
    unsigned o = __hip_atomic_fetch_add(done, 1u, __ATOMIC_ACQ_REL, __HIP_MEMORY_SCOPE_AGENT);
    lastf = (o == (unsigned)(NBLKS - 1)) ? 1u : 0u;
  }
  __syncthreads();

  // ---- last block deterministically sums the 256 loss partials ----
  if (lastf) {
    float v = (tid < NBLKS) ? ldg1(&lpart[tid]) : 0.f;
#pragma unroll
    for (int msk = 32; msk; msk >>= 1) v += __shfl_down(v, msk, 64);
    if (tid < NBLKS && (tid & 63) == 0) lsum[tid >> 6] = v;
    __syncthreads();
    if (tid == 0) {
      float s = 0.f;
#pragma unroll
      for (int k2 = 0; k2 < 4; ++k2) s += lsum[k2];
      out[0] = s / (float)N;
    }
  }
}

extern "C" void kernel_launch(void* const* d_in, const int* in_sizes, int n_in,
                              void* d_out, int out_size, void* d_ws, size_t ws_size,
                              hipStream_t stream)
{
  (void)in_sizes; (void)n_in; (void)out_size; (void)ws_size;
  const float* x    = (const float*)d_in[0];
  const int*   tgt  = (const int*)d_in[1];
  const float* marg = (const float*)d_in[2];
  const float* wgt  = (const float*)d_in[3];
  const int*   hm   = (const int*)d_in[4];
  float* out = (float*)d_out;

  ushort*   xf    = (ushort*)d_ws;                          // 1 MB fragment-linear bf16-hi
  float*    lpart = (float*)((char*)d_ws + (1 << 20));      // 256 loss partials
  unsigned* done  = (unsigned*)(lpart + NBLKS);             // 1 counter

  k_conv<<<256, 256, 0, stream>>>(x, xf, done);
  k_main<<<NBLKS, 1024, 0, stream>>>(x, tgt, marg, wgt, hm, out, xf, lpart, done);
}

// Round 17
// 43.184 us; speedup vs baseline: 1.6191x; 1.0052x over previous
//
#include <hip/hip_runtime.h>
#include <math.h>

#define N 4096
#define D 128
#define NROW 16               // rows per block
#define NBLKS 256             // main-kernel grid (one 16-row panel per block)
#define BIGV 1e30f

typedef __bf16 bf16x8 __attribute__((ext_vector_type(8)));
typedef float  f32x4  __attribute__((ext_vector_type(4)));
typedef __attribute__((address_space(3))) unsigned lds_u32;
typedef const __attribute__((address_space(1))) unsigned glb_u32;

__device__ __forceinline__ void stg(float* p, float v) {
  __hip_atomic_store(p, v, __ATOMIC_RELAXED, __HIP_MEMORY_SCOPE_AGENT);
}
__device__ __forceinline__ float ldg1(const float* p) {
  return __hip_atomic_load((float*)p, __ATOMIC_RELAXED, __HIP_MEMORY_SCOPE_AGENT);
}

// ---- DPP 16-lane reductions (VALU pipe, no LDS traffic): xor1, xor2, ror4, ror8 ----
template<int CTRL>
__device__ __forceinline__ float dppf(float v) {
  int r = __builtin_amdgcn_update_dpp(0, __float_as_int(v), CTRL, 0xF, 0xF, true);
  return __int_as_float(r);
}
__device__ __forceinline__ float rsum16(float v) {
  v += dppf<0xB1>(v);   // quad_perm [1,0,3,2]
  v += dppf<0x4E>(v);   // quad_perm [2,3,0,1]
  v += dppf<0x124>(v);  // row_ror:4
  v += dppf<0x128>(v);  // row_ror:8
  return v;
}
__device__ __forceinline__ float rmin16(float v) {
  v = fminf(v, dppf<0xB1>(v));
  v = fminf(v, dppf<0x4E>(v));
  v = fminf(v, dppf<0x124>(v));
  v = fminf(v, dppf<0x128>(v));
  return v;
}
__device__ __forceinline__ float rmax16(float v) {
  v = fmaxf(v, dppf<0xB1>(v));
  v = fmaxf(v, dppf<0x4E>(v));
  v = fmaxf(v, dppf<0x124>(v));
  v = fmaxf(v, dppf<0x128>(v));
  return v;
}

// split 8 f32 -> 8 bf16 hi + 8 bf16 lo (rne/rne; proven bit-exact path)
__device__ __forceinline__ void cvt8(float4 v0, float4 v1, int4& hp, int4& lp) {
  float vf[8] = {v0.x, v0.y, v0.z, v0.w, v1.x, v1.y, v1.z, v1.w};
  unsigned h[8], l[8];
#pragma unroll
  for (int i = 0; i < 8; ++i) {
    unsigned u = __float_as_uint(vf[i]);
    unsigned hr = (u + 0x7FFFu + ((u >> 16) & 1u)) >> 16;
    float hv = __uint_as_float(hr << 16);
    unsigned ul = __float_as_uint(vf[i] - hv);
    l[i] = (ul + 0x7FFFu + ((ul >> 16) & 1u)) >> 16;
    h[i] = hr;
  }
  hp = make_int4((int)(h[0] | (h[1] << 16)), (int)(h[2] | (h[3] << 16)),
                 (int)(h[4] | (h[5] << 16)), (int)(h[6] | (h[7] << 16)));
  lp = make_int4((int)(l[0] | (l[1] << 16)), (int)(l[2] | (l[3] << 16)),
                 (int)(l[4] | (l[5] << 16)), (int)(l[6] | (l[7] << 16)));
}
__device__ __forceinline__ void cvt8hi(float4 v0, float4 v1, int4& hp) {
  float vf[8] = {v0.x, v0.y, v0.z, v0.w, v1.x, v1.y, v1.z, v1.w};
  unsigned h[8];
#pragma unroll
  for (int i = 0; i < 8; ++i) {
    unsigned u = __float_as_uint(vf[i]);
    h[i] = (u + 0x7FFFu + ((u >> 16) & 1u)) >> 16;
  }
  hp = make_int4((int)(h[0] | (h[1] << 16)), (int)(h[2] | (h[3] << 16)),
                 (int)(h[4] | (h[5] << 16)), (int)(h[6] | (h[7] << 16)));
}

// ---- convert kernel: x -> bf16-hi in MFMA-fragment-linear order ----
// unit = ((C>>4)*4 + (k16>>2))*64 + (k16&3)*16 + (C&15); 16B per unit.
// Also resets the done-counter (replaces a separate memset dispatch).
__global__ __launch_bounds__(256)
void k_conv(const float* __restrict__ x, ushort* __restrict__ xf, unsigned* done)
{
  if (blockIdx.x == 0 && threadIdx.x == 0)
    __hip_atomic_store(done, 0u, __ATOMIC_RELAXED, __HIP_MEMORY_SCOPE_AGENT);
  int gid = blockIdx.x * 256 + threadIdx.x;     // 65536 = 4096 C x 16 k16
  int C = gid >> 4, k16 = gid & 15;
  const float* ap = x + C * D + k16 * 8;
  float4 v0 = *(const float4*)ap, v1 = *(const float4*)(ap + 4);
  int4 hp;
  cvt8hi(v0, v1, hp);
  int unit = ((C >> 4) * 4 + (k16 >> 2)) * 64 + (k16 & 3) * 16 + (C & 15);
  *(int4*)((char*)xf + ((size_t)unit << 4)) = hp;
}

#define VMCNT(n) asm volatile("s_waitcnt vmcnt(" #n ")" ::: "memory")

// stage tile ct_ (4 KB: 4 kt x 64 lanes x 16B) into wave-private buffer b_
#define STAGE(b_, ct_) do {                                                        \
    const char* gsrc_ = (const char*)xf + ((size_t)(ct_) << 12) + (l << 4);        \
    char* ldst_ = bbase + ((b_) << 12);                                            \
    _Pragma("unroll")                                                              \
    for (int kt_ = 0; kt_ < 4; ++kt_)                                              \
      __builtin_amdgcn_global_load_lds((glb_u32*)(gsrc_ + (kt_ << 10)),            \
                                       (lds_u32*)(ldst_ + (kt_ << 10)), 16, 0, 0); \
  } while (0)

__global__ __launch_bounds__(1024, 1)
void k_main(const float* __restrict__ x, const int* __restrict__ tgt,
            const float* __restrict__ marg, const float* __restrict__ wgt,
            const int* __restrict__ hm, float* __restrict__ out,
            const ushort* __restrict__ xf, float* __restrict__ lpart,
            unsigned* __restrict__ done)
{
  __shared__ __bf16 Bbuf[16][2][2048];          // 16 waves x 2 x 4 KB = 128 KB
  __shared__ float redA[16][16], redB[16][16], redC[16][16], redD[16][16];
  __shared__ float finMn[16], finMx[16], lsRow[16];
  __shared__ float lsum[4];
  __shared__ unsigned lastf;

  const int tid = threadIdx.x;
  const int bid = blockIdx.x;
  const int w = tid >> 6, l = tid & 63;     // 16 waves; wave w owns cols [w*256, w*256+256)
  const int c = l & 15, g = l >> 4;
  const int i0 = bid * NROW;
  char* bbase = (char*)&Bbuf[w][0][0];

  // per-thread row metadata (direct global; lanes with equal g broadcast-coalesce)
  int trow[4];
#pragma unroll
  for (int jj = 0; jj < 4; ++jj) trow[jj] = tgt[i0 + g * 4 + jj];

  // ---- A fragments (16 rows, hi+lo) in registers: row i0+c, k = kt*32 + g*8 ----
  bf16x8 Ah[4], Al[4];
#pragma unroll
  for (int kt = 0; kt < 4; ++kt) {
    const float* ap = x + (i0 + c) * D + kt * 32 + g * 8;
    float4 v0 = *(const float4*)ap, v1 = *(const float4*)(ap + 4);
    int4 hp, lp;
    cvt8(v0, v1, hp, lp);
    Ah[kt] = *(bf16x8*)&hp;
    Al[kt] = *(bf16x8*)&lp;
  }

  f32x4 acc[16];
#pragma unroll
  for (int ci = 0; ci < 16; ++ci) acc[ci] = f32x4{0.f, 0.f, 0.f, 0.f};

  float mn4[4], mx4[4];
#pragma unroll
  for (int jj = 0; jj < 4; ++jj) { mn4[jj] = BIGV; mx4[jj] = -BIGV; }

  // ---- K-loop: LDS dbuf + counted vmcnt(5) (4 stage + 1 tgt per tile), no barriers.
  //      Pass-1 (min/max scan) fused after each tile's MFMAs. No sched_barriers:
  //      the asm "memory" clobber orders memory ops; the compiler is free to
  //      software-pipeline scan(ci) into stage(ci+1)'s latency window.
  STAGE(0, (w << 4));
  int tc_next = tgt[(w << 4) * 16 + c];
#pragma unroll
  for (int ci = 0; ci < 16; ++ci) {
    const int tc_cur = tc_next;
    if (ci + 1 < 16) {
      STAGE((ci + 1) & 1, (w << 4) + ci + 1);
      tc_next = tgt[((w << 4) + ci + 1) * 16 + c];
      VMCNT(5);                 // drains tile ci's 4 stages + tc_cur; next 5 in flight
    } else {
      VMCNT(0);
    }
    const int ct = (w << 4) + ci;
    if (ct == bid) {
      // diagonal tile: B-frags are the A-frag registers -> exact 3-product
#pragma unroll
      for (int kt = 0; kt < 4; ++kt) {
        acc[ci] = __builtin_amdgcn_mfma_f32_16x16x32_bf16(Ah[kt], Ah[kt], acc[ci], 0, 0, 0);
        acc[ci] = __builtin_amdgcn_mfma_f32_16x16x32_bf16(Ah[kt], Al[kt], acc[ci], 0, 0, 0);
        acc[ci] = __builtin_amdgcn_mfma_f32_16x16x32_bf16(Al[kt], Ah[kt], acc[ci], 0, 0, 0);
      }
    } else {
      const char* bp = bbase + ((ci & 1) << 12) + (l << 4);
#pragma unroll
      for (int kt = 0; kt < 4; ++kt) {
        bf16x8 Bh = *(const bf16x8*)(bp + (kt << 10));
        acc[ci] = __builtin_amdgcn_mfma_f32_16x16x32_bf16(Ah[kt], Bh, acc[ci], 0, 0, 0);
        acc[ci] = __builtin_amdgcn_mfma_f32_16x16x32_bf16(Al[kt], Bh, acc[ci], 0, 0, 0);
      }
    }
    // fused pass-1: acc[ci] is final for this tile
#pragma unroll
    for (int jj = 0; jj < 4; ++jj) {
      float s = acc[ci][jj];
      if (tc_cur == trow[jj]) { if (s < 1.0f) mn4[jj] = fminf(mn4[jj], s); }
      else                      mx4[jj] = fmaxf(mx4[jj], s);
    }
  }

  // ---- cross-lane (DPP) + cross-wave min/max reduction ----
#pragma unroll
  for (int jj = 0; jj < 4; ++jj) {
    mn4[jj] = rmin16(mn4[jj]);
    mx4[jj] = rmax16(mx4[jj]);
  }
  if (c == 0) {
#pragma unroll
    for (int jj = 0; jj < 4; ++jj) {
      redA[w][g * 4 + jj] = mn4[jj];
      redB[w][g * 4 + jj] = mx4[jj];
    }
  }
  __syncthreads();
  if (tid < 16) {
    float mn = BIGV, mx = -BIGV;
#pragma unroll
    for (int w16 = 0; w16 < 16; ++w16) {
      mn = fminf(mn, redA[w16][tid]);
      mx = fmaxf(mx, redB[w16][tid]);
    }
    finMn[tid] = mn; finMx[tid] = mx;
  }
  __syncthreads();

  // ---- mining epilogue over the same in-register acc ----
  const int mode = hm[0];
  float mnp[4], mxn[4], mg4[4], wt4[4];
  float ps4[4], ns4[4], ap4[4], an4[4];
#pragma unroll
  for (int jj = 0; jj < 4; ++jj) {
    int r = g * 4 + jj;
    mnp[jj] = finMn[r]; mxn[jj] = finMx[r];
    mg4[jj] = marg[i0 + r]; wt4[jj] = wgt[i0 + r];
    ps4[jj] = 0.f; ns4[jj] = 0.f; ap4[jj] = 0.f; an4[jj] = 0.f;
  }
#pragma unroll
  for (int ci = 0; ci < 16; ++ci) {
    int tc = tgt[((w << 4) + ci) * 16 + c];    // L1-hot (touched in K-loop)
#pragma unroll
    for (int jj = 0; jj < 4; ++jj) {
      float s = acc[ci][jj];
      bool same = (tc == trow[jj]);
      if (mode == 1) {
        float wsim = s * wt4[jj];
        if (same) {
          if (s < 1.0f && (mxn[jj] - s + mg4[jj] > 0.f)) {
            ps4[jj] += __expf(-2.f * (wsim - 0.5f)); ap4[jj] += 1.f;
          }
        } else {
          if (s + mg4[jj] - mnp[jj] > 0.f) {
            ns4[jj] += __expf(10.f * (wsim - 0.5f)); an4[jj] += 1.f;
          }
        }
      } else {
        if (same) {
          if (s < 1.0f) { ps4[jj] += __expf(-2.f * (s - 0.5f - mg4[jj])); ap4[jj] += 1.f; }
        } else {
          ns4[jj] += __expf(10.f * (s - 0.5f + mg4[jj])); an4[jj] += 1.f;
        }
      }
    }
  }
#pragma unroll
  for (int jj = 0; jj < 4; ++jj) {
    ps4[jj] = rsum16(ps4[jj]);
    ns4[jj] = rsum16(ns4[jj]);
    ap4[jj] = rsum16(ap4[jj]);
    an4[jj] = rsum16(an4[jj]);
  }
  if (c == 0) {
#pragma unroll
    for (int jj = 0; jj < 4; ++jj) {
      int r = g * 4 + jj;
      redA[w][r] = ps4[jj]; redB[w][r] = ns4[jj];
      redC[w][r] = ap4[jj]; redD[w][r] = an4[jj];
    }
  }
  __syncthreads();
  if (tid < 16) {
    float ps = 0.f, ns = 0.f, ap = 0.f, an = 0.f;
#pragma unroll
    for (int w16 = 0; w16 < 16; ++w16) {
      ps += redA[w16][tid]; ns += redB[w16][tid];
      ap += redC[w16][tid]; an += redD[w16][tid];
    }
    float loss_i = 1.0f * log1pf(ps) + 0.2f * log1pf(ns);
    if (mode == 1 && (ap + an) < 1.0f) { loss_i = 0.f; ap = 0.f; an = 0.f; }
    out[1 + i0 + tid]     = ap;
    out[1 + N + i0 + tid] = an;
    lsRow[tid] = loss_i;
  }
  __syncthreads();
  if (tid == 0) {
    float lb = 0.f;
#pragma unroll
    for (int r = 0; r < 16; ++r) lb += lsRow[r];
    stg(&lpart[bid], lb);
    asm volatile("s_waitcnt vmcnt(0)" ::: "memory");
    unsigned o = __hip_atomic_fetch_add(done, 1u, __ATOMIC_ACQ_REL, __HIP_MEMORY_SCOPE_AGENT);
    lastf = (o == (unsigned)(NBLKS - 1)) ? 1u : 0u;
  }
  __syncthreads();

  // ---- last block deterministically sums the 256 loss partials ----
  if (lastf) {
    float v = (tid < NBLKS) ? ldg1(&lpart[tid]) : 0.f;
#pragma unroll
    for (int msk = 32; msk; msk >>= 1) v += __shfl_down(v, msk, 64);
    if (tid < NBLKS && (tid & 63) == 0) lsum[tid >> 6] = v;
    __syncthreads();
    if (tid == 0) {
      float s = 0.f;
#pragma unroll
      for (int k2 = 0; k2 < 4; ++k2) s += lsum[k2];
      out[0] = s / (float)N;
    }
  }
}

extern "C" void kernel_launch(void* const* d_in, const int* in_sizes, int n_in,
                              void* d_out, int out_size, void* d_ws, size_t ws_size,
                              hipStream_t stream)
{
  (void)in_sizes; (void)n_in; (void)out_size; (void)ws_size;
  const float* x    = (const float*)d_in[0];
  const int*   tgt  = (const int*)d_in[1];
  const float* marg = (const float*)d_in[2];
  const float* wgt  = (const float*)d_in[3];
  const int*   hm   = (const int*)d_in[4];
  float* out = (float*)d_out;

  ushort*   xf    = (ushort*)d_ws;                          // 1 MB fragment-linear bf16-hi
  float*    lpart = (float*)((char*)d_ws + (1 << 20));      // 256 loss partials
  unsigned* done  = (unsigned*)(lpart + NBLKS);             // 1 counter

  k_conv<<<256, 256, 0, stream>>>(x, xf, done);
  k_main<<<NBLKS, 1024, 0, stream>>>(x, tgt, marg, wgt, hm, out, xf, lpart, done);
}